// Round 1
// baseline (1719.358 us; speedup 1.0000x reference)
//
#include <hip/hip_runtime.h>
#include <math.h>

#define N_NODES 100000
#define N_EDGES 1600000
#define F_IN 128
#define F_E 8
#define HC 64      // H*C (layer-1 output width)
#define NHEAD 4
#define NEG 0.2f

// ---- ordered-uint encoding for float atomicMax ----
__device__ __forceinline__ unsigned fenc(float f) {
    unsigned b = __float_as_uint(f);
    return (b & 0x80000000u) ? ~b : (b | 0x80000000u);
}
__device__ __forceinline__ float fdec(unsigned u) {
    unsigned b = (u & 0x80000000u) ? (u ^ 0x80000000u) : ~u;
    return __uint_as_float(b);
}

__global__ void zero_kernel(float4* __restrict__ p, int count4) {
    int stride = gridDim.x * blockDim.x;
    for (int i = blockIdx.x * blockDim.x + threadIdx.x; i < count4; i += stride)
        p[i] = make_float4(0.f, 0.f, 0.f, 0.f);
}

// sum edge_attr over rows -> sum8 (divide by E at point of use)
__global__ void mean_sum_kernel(const float* __restrict__ ea, float* __restrict__ sum8) {
    float acc[8] = {0.f,0.f,0.f,0.f,0.f,0.f,0.f,0.f};
    int stride = gridDim.x * blockDim.x;
    for (int r = blockIdx.x * blockDim.x + threadIdx.x; r < N_EDGES; r += stride) {
        const float4* p = (const float4*)(ea + (size_t)r * 8);
        float4 a = p[0], b = p[1];
        acc[0] += a.x; acc[1] += a.y; acc[2] += a.z; acc[3] += a.w;
        acc[4] += b.x; acc[5] += b.y; acc[6] += b.z; acc[7] += b.w;
    }
#pragma unroll
    for (int k = 0; k < 8; k++) {
        float v = acc[k];
        for (int off = 32; off; off >>= 1) v += __shfl_down(v, off);
        if ((threadIdx.x & 63) == 0) atomicAdd(&sum8[k], v);
    }
}

// xl = x@Wl + bl ; xr = x@Wr + br    (N x 128) @ (128 x 64)
__global__ void gemm1_kernel(const float* __restrict__ x,
                             const float* __restrict__ Wl, const float* __restrict__ bl,
                             const float* __restrict__ Wr, const float* __restrict__ br,
                             float* __restrict__ xl, float* __restrict__ xr) {
    __shared__ float Wb[F_IN][2 * HC];   // 128x128 f32 = 64 KiB
    __shared__ float xrow[2][F_IN];
    for (int i = threadIdx.x; i < F_IN * HC; i += blockDim.x) {
        int k = i / HC, j = i % HC;
        Wb[k][j]      = Wl[i];
        Wb[k][j + HC] = Wr[i];
    }
    __syncthreads();
    int group = threadIdx.x >> 7;     // 0..1 (node within pair)
    int j     = threadIdx.x & 127;    // combined output column
    float bias = (j < HC) ? bl[j] : br[j - HC];
    for (int n0 = blockIdx.x * 2; n0 < N_NODES; n0 += gridDim.x * 2) {
        int n = n0 + group;
        if (n < N_NODES) xrow[group][j] = x[(size_t)n * F_IN + j];
        __syncthreads();
        if (n < N_NODES) {
            float acc = bias;
#pragma unroll 16
            for (int k = 0; k < F_IN; k++) acc += xrow[group][k] * Wb[k][j];
            if (j < HC) xl[(size_t)n * HC + j] = acc;
            else        xr[(size_t)n * HC + (j - HC)] = acc;
        }
        __syncthreads();
    }
}

// one wave per item (E real edges + N self loops): logits + atomicMax m
__global__ void edge_logits1(const int* __restrict__ src, const int* __restrict__ dst,
                             const float* __restrict__ ea, const float* __restrict__ sum8,
                             const float* __restrict__ We, const float* __restrict__ att,
                             const float* __restrict__ xl, const float* __restrict__ xr,
                             float* __restrict__ logits, unsigned* __restrict__ m) {
    int gt = blockIdx.x * blockDim.x + threadIdx.x;
    int item = gt >> 6;
    int lane = threadIdx.x & 63;
    if (item >= N_EDGES + N_NODES) return;
    int s, d;
    float a[8];
    if (item < N_EDGES) {
        s = src[item]; d = dst[item];
        const float4* p = (const float4*)(ea + (size_t)item * 8);
        float4 u = p[0], v4 = p[1];
        a[0]=u.x; a[1]=u.y; a[2]=u.z; a[3]=u.w; a[4]=v4.x; a[5]=v4.y; a[6]=v4.z; a[7]=v4.w;
    } else {
        s = d = item - N_EDGES;
        const float inv = 1.0f / N_EDGES;
#pragma unroll
        for (int k = 0; k < 8; k++) a[k] = sum8[k] * inv;
    }
    float ee = 0.f;
#pragma unroll
    for (int k = 0; k < 8; k++) ee += a[k] * We[k * HC + lane];
    float v = xl[(size_t)s * HC + lane] + xr[(size_t)d * HC + lane] + ee;
    v = v > 0.f ? v : NEG * v;
    float prod = v * att[lane];
    prod += __shfl_xor(prod, 1);
    prod += __shfl_xor(prod, 2);
    prod += __shfl_xor(prod, 4);
    prod += __shfl_xor(prod, 8);
    if ((lane & 15) == 0) {
        int h = lane >> 4;
        logits[(size_t)item * NHEAD + h] = prod;
        atomicMax(&m[(size_t)d * NHEAD + h], fenc(prod));
    }
}

// one wave per real edge: p = exp(logit-m); atomic denom + feature accumulation
__global__ void edge_accum1(const int* __restrict__ src, const int* __restrict__ dst,
                            const float* __restrict__ logits, const unsigned* __restrict__ m,
                            const float* __restrict__ xl,
                            float* __restrict__ denom, float* __restrict__ acc) {
    int gt = blockIdx.x * blockDim.x + threadIdx.x;
    int e = gt >> 6;
    int lane = threadIdx.x & 63;
    if (e >= N_EDGES) return;
    int s = src[e], d = dst[e];
    int h = lane >> 4;
    float logit = logits[(size_t)e * NHEAD + h];
    float mm = fdec(m[(size_t)d * NHEAD + h]);
    float p = expf(logit - mm);
    if ((lane & 15) == 0) atomicAdd(&denom[(size_t)d * NHEAD + h], p);
    atomicAdd(&acc[(size_t)d * HC + lane], p * xl[(size_t)s * HC + lane]);
}

// one wave per node: add self-loop contribution, normalize, +bias, ELU,
// then fused layer-2 projections xl2/xr2 (64->1 each) via wave reduction.
__global__ void finalize1(const float* __restrict__ xl, const float* __restrict__ logits,
                          const unsigned* __restrict__ m, const float* __restrict__ denom,
                          const float* __restrict__ b1,
                          float* __restrict__ h_acc,   // acc in, h1 out (in place)
                          const float* __restrict__ Wl2, const float* __restrict__ bl2,
                          const float* __restrict__ Wr2, const float* __restrict__ br2,
                          float* __restrict__ xl2, float* __restrict__ xr2) {
    int gt = blockIdx.x * blockDim.x + threadIdx.x;
    int i = gt >> 6;
    int lane = threadIdx.x & 63;
    if (i >= N_NODES) return;
    int h = lane >> 4;
    float logit_self = logits[(size_t)(N_EDGES + i) * NHEAD + h];
    float mm = fdec(m[(size_t)i * NHEAD + h]);
    float p = expf(logit_self - mm);
    float den = denom[(size_t)i * NHEAD + h] + p;
    float xlv = xl[(size_t)i * HC + lane];
    float o = (h_acc[(size_t)i * HC + lane] + p * xlv) / den + b1[lane];
    o = o > 0.f ? o : expm1f(o);                 // ELU (alpha=1)
    h_acc[(size_t)i * HC + lane] = o;
    float sl = o * Wl2[lane];
    float sr = o * Wr2[lane];
    for (int off = 32; off; off >>= 1) {
        sl += __shfl_down(sl, off);
        sr += __shfl_down(sr, off);
    }
    if (lane == 0) {
        xl2[i] = sl + bl2[0];
        xr2[i] = sr + br2[0];
    }
}

// one THREAD per item (E + N): layer-2 logits + atomicMax m2
__global__ void edge_logits2(const int* __restrict__ src, const int* __restrict__ dst,
                             const float* __restrict__ ea, const float* __restrict__ sum8,
                             const float* __restrict__ We2, const float* __restrict__ att2,
                             const float* __restrict__ xl2, const float* __restrict__ xr2,
                             float* __restrict__ logits2, unsigned* __restrict__ m2) {
    int item = blockIdx.x * blockDim.x + threadIdx.x;
    if (item >= N_EDGES + N_NODES) return;
    int s, d;
    float ee = 0.f;
    if (item < N_EDGES) {
        s = src[item]; d = dst[item];
        const float4* p = (const float4*)(ea + (size_t)item * 8);
        float4 u = p[0], v4 = p[1];
        ee = u.x*We2[0] + u.y*We2[1] + u.z*We2[2] + u.w*We2[3]
           + v4.x*We2[4] + v4.y*We2[5] + v4.z*We2[6] + v4.w*We2[7];
    } else {
        s = d = item - N_EDGES;
        const float inv = 1.0f / N_EDGES;
#pragma unroll
        for (int k = 0; k < 8; k++) ee += sum8[k] * inv * We2[k];
    }
    float v = xl2[s] + xr2[d] + ee;
    v = v > 0.f ? v : NEG * v;
    float logit = att2[0] * v;
    logits2[item] = logit;
    atomicMax(&m2[d], fenc(logit));
}

__global__ void edge_accum2(const int* __restrict__ src, const int* __restrict__ dst,
                            const float* __restrict__ logits2, const unsigned* __restrict__ m2,
                            const float* __restrict__ xl2,
                            float* __restrict__ denom2, float* __restrict__ num2) {
    int e = blockIdx.x * blockDim.x + threadIdx.x;
    if (e >= N_EDGES) return;
    int s = src[e], d = dst[e];
    float p = expf(logits2[e] - fdec(m2[d]));
    atomicAdd(&denom2[d], p);
    atomicAdd(&num2[d], p * xl2[s]);
}

__global__ void finalize2(const float* __restrict__ logits2, const unsigned* __restrict__ m2,
                          const float* __restrict__ denom2, const float* __restrict__ num2,
                          const float* __restrict__ xl2, const float* __restrict__ b2,
                          float* __restrict__ out) {
    int i = blockIdx.x * blockDim.x + threadIdx.x;
    if (i >= N_NODES) return;
    float p = expf(logits2[N_EDGES + i] - fdec(m2[i]));
    out[i] = (num2[i] + p * xl2[i]) / (denom2[i] + p) + b2[0];
}

extern "C" void kernel_launch(void* const* d_in, const int* in_sizes, int n_in,
                              void* d_out, int out_size, void* d_ws, size_t ws_size,
                              hipStream_t stream) {
    const float* x    = (const float*)d_in[0];
    const int*   ei   = (const int*)d_in[1];
    const float* ea   = (const float*)d_in[2];
    const float* Wl1  = (const float*)d_in[3];
    const float* bl1  = (const float*)d_in[4];
    const float* Wr1  = (const float*)d_in[5];
    const float* br1  = (const float*)d_in[6];
    const float* We1  = (const float*)d_in[7];
    const float* att1 = (const float*)d_in[8];
    const float* b1   = (const float*)d_in[9];
    const float* Wl2  = (const float*)d_in[10];
    const float* bl2  = (const float*)d_in[11];
    const float* Wr2  = (const float*)d_in[12];
    const float* br2  = (const float*)d_in[13];
    const float* We2  = (const float*)d_in[14];
    const float* att2 = (const float*)d_in[15];
    const float* b2   = (const float*)d_in[16];

    const int* src = ei;              // edge_index row 0
    const int* dst = ei + N_EDGES;    // edge_index row 1

    float* W = (float*)d_ws;
    size_t o = 0;
    float*    sum8    = W + o;               o += 8;
    unsigned* m1      = (unsigned*)(W + o);  o += (size_t)N_NODES * NHEAD;
    float*    denom1  = W + o;               o += (size_t)N_NODES * NHEAD;
    float*    acc1    = W + o;               o += (size_t)N_NODES * HC;    // -> h1
    unsigned* m2      = (unsigned*)(W + o);  o += N_NODES;
    float*    denom2  = W + o;               o += N_NODES;
    float*    num2    = W + o;               o += N_NODES;
    size_t zero_count = o;                   // everything above needs zeroing each call
    float*    xl1     = W + o;               o += (size_t)N_NODES * HC;
    float*    xr1     = W + o;               o += (size_t)N_NODES * HC;
    float*    logits1 = W + o;               o += (size_t)(N_EDGES + N_NODES) * NHEAD;
    float*    xl2     = W + o;               o += N_NODES;
    float*    xr2     = W + o;               o += N_NODES;
    float*    logits2 = W + o;               o += (size_t)(N_EDGES + N_NODES);

    int items = N_EDGES + N_NODES;

    zero_kernel<<<2048, 256, 0, stream>>>((float4*)W, (int)(zero_count / 4) + 1);
    mean_sum_kernel<<<1024, 256, 0, stream>>>(ea, sum8);
    gemm1_kernel<<<2048, 256, 0, stream>>>(x, Wl1, bl1, Wr1, br1, xl1, xr1);
    edge_logits1<<<(items * 64 + 255) / 256, 256, 0, stream>>>(
        src, dst, ea, sum8, We1, att1, xl1, xr1, logits1, m1);
    edge_accum1<<<(N_EDGES * 64 + 255) / 256, 256, 0, stream>>>(
        src, dst, logits1, m1, xl1, denom1, acc1);
    finalize1<<<(N_NODES * 64 + 255) / 256, 256, 0, stream>>>(
        xl1, logits1, m1, denom1, b1, acc1, Wl2, bl2, Wr2, br2, xl2, xr2);
    edge_logits2<<<(items + 255) / 256, 256, 0, stream>>>(
        src, dst, ea, sum8, We2, att2, xl2, xr2, logits2, m2);
    edge_accum2<<<(N_EDGES + 255) / 256, 256, 0, stream>>>(
        src, dst, logits2, m2, xl2, denom2, num2);
    finalize2<<<(N_NODES + 255) / 256, 256, 0, stream>>>(
        logits2, m2, denom2, num2, xl2, b2, (float*)d_out);
}

// Round 2
// 1053.828 us; speedup vs baseline: 1.6315x; 1.6315x over previous
//
#include <hip/hip_runtime.h>
#include <math.h>

#define N_NODES 100000
#define N_EDGES 1600000
#define N_ITEMS (N_EDGES + N_NODES)   // edges + self loops
#define F_IN 128
#define F_E 8
#define HC 64      // H*C (layer-1 output width)
#define NHEAD 4
#define NEG 0.2f
#define SCAN_BS 1024
#define SCAN_NB ((N_NODES + SCAN_BS - 1) / SCAN_BS)   // 98

__global__ void zero_sum8(float* __restrict__ sum8) {
    if (threadIdx.x < 8) sum8[threadIdx.x] = 0.f;
}

__global__ void init_deg(unsigned* __restrict__ deg) {
    int i = blockIdx.x * blockDim.x + threadIdx.x;
    if (i < N_NODES) deg[i] = 1u;   // self loop
}

// sum edge_attr over rows -> sum8 (divide by E at point of use)
__global__ void mean_sum_kernel(const float* __restrict__ ea, float* __restrict__ sum8) {
    float acc[8] = {0.f,0.f,0.f,0.f,0.f,0.f,0.f,0.f};
    int stride = gridDim.x * blockDim.x;
    for (int r = blockIdx.x * blockDim.x + threadIdx.x; r < N_EDGES; r += stride) {
        const float4* p = (const float4*)(ea + (size_t)r * 8);
        float4 a = p[0], b = p[1];
        acc[0] += a.x; acc[1] += a.y; acc[2] += a.z; acc[3] += a.w;
        acc[4] += b.x; acc[5] += b.y; acc[6] += b.z; acc[7] += b.w;
    }
#pragma unroll
    for (int k = 0; k < 8; k++) {
        float v = acc[k];
        for (int off = 32; off; off >>= 1) v += __shfl_down(v, off);
        if ((threadIdx.x & 63) == 0) atomicAdd(&sum8[k], v);
    }
}

__global__ void hist_kernel(const int* __restrict__ dst, unsigned* __restrict__ deg) {
    int e = blockIdx.x * blockDim.x + threadIdx.x;
    if (e < N_EDGES) atomicAdd(&deg[dst[e]], 1u);
}

// inclusive block scan of deg -> local_inc; per-block totals -> bsum
__global__ void scan1(const unsigned* __restrict__ deg, unsigned* __restrict__ local_inc,
                      unsigned* __restrict__ bsum) {
    __shared__ unsigned tmp[SCAN_BS];
    int i = blockIdx.x * SCAN_BS + threadIdx.x;
    unsigned v = (i < N_NODES) ? deg[i] : 0u;
    tmp[threadIdx.x] = v;
    __syncthreads();
    for (int off = 1; off < SCAN_BS; off <<= 1) {
        unsigned add = (threadIdx.x >= (unsigned)off) ? tmp[threadIdx.x - off] : 0u;
        __syncthreads();
        tmp[threadIdx.x] += add;
        __syncthreads();
    }
    if (i < N_NODES) local_inc[i] = tmp[threadIdx.x];
    if (threadIdx.x == SCAN_BS - 1) bsum[blockIdx.x] = tmp[threadIdx.x];
}

// exclusive scan of the 98 block sums (single block of 128)
__global__ void scan2(unsigned* __restrict__ bsum) {
    __shared__ unsigned tmp[128];
    int t = threadIdx.x;
    unsigned v = (t < SCAN_NB) ? bsum[t] : 0u;
    tmp[t] = v;
    __syncthreads();
    for (int off = 1; off < 128; off <<= 1) {
        unsigned add = (t >= off) ? tmp[t - off] : 0u;
        __syncthreads();
        tmp[t] += add;
        __syncthreads();
    }
    if (t < SCAN_NB) bsum[t] = tmp[t] - v;   // exclusive
}

__global__ void scan3(const unsigned* __restrict__ local_inc, const unsigned* __restrict__ deg,
                      const unsigned* __restrict__ bsum,
                      unsigned* __restrict__ row_start, unsigned* __restrict__ next) {
    int i = blockIdx.x * blockDim.x + threadIdx.x;
    if (i >= N_NODES) return;
    unsigned v = local_inc[i] - deg[i] + bsum[i / SCAN_BS];
    row_start[i] = v;
    next[i] = v;
}

// scatter edges (+ self loops) into destination-sorted order
__global__ void scatter_kernel(const int* __restrict__ src, const int* __restrict__ dst,
                               const float* __restrict__ ea, const float* __restrict__ sum8,
                               unsigned* __restrict__ next,
                               int* __restrict__ sorted_src, float* __restrict__ sorted_ea) {
    int item = blockIdx.x * blockDim.x + threadIdx.x;
    if (item >= N_ITEMS) return;
    int s, d;
    float4 a, b;
    if (item < N_EDGES) {
        s = src[item]; d = dst[item];
        const float4* p = (const float4*)(ea + (size_t)item * 8);
        a = p[0]; b = p[1];
    } else {
        s = d = item - N_EDGES;
        const float inv = 1.0f / N_EDGES;
        a = make_float4(sum8[0]*inv, sum8[1]*inv, sum8[2]*inv, sum8[3]*inv);
        b = make_float4(sum8[4]*inv, sum8[5]*inv, sum8[6]*inv, sum8[7]*inv);
    }
    unsigned pos = atomicAdd(&next[d], 1u);
    sorted_src[pos] = s;
    float4* q = (float4*)(sorted_ea + (size_t)pos * 8);
    q[0] = a; q[1] = b;
}

// xl = x@Wl + bl ; xr = x@Wr + br    (N x 128) @ (128 x 64)
__global__ void gemm1_kernel(const float* __restrict__ x,
                             const float* __restrict__ Wl, const float* __restrict__ bl,
                             const float* __restrict__ Wr, const float* __restrict__ br,
                             float* __restrict__ xl, float* __restrict__ xr) {
    __shared__ float Wb[F_IN][2 * HC];   // 128x128 f32 = 64 KiB
    __shared__ float xrow[2][F_IN];
    for (int i = threadIdx.x; i < F_IN * HC; i += blockDim.x) {
        int k = i / HC, j = i % HC;
        Wb[k][j]      = Wl[i];
        Wb[k][j + HC] = Wr[i];
    }
    __syncthreads();
    int group = threadIdx.x >> 7;     // 0..1 (node within pair)
    int j     = threadIdx.x & 127;    // combined output column
    float bias = (j < HC) ? bl[j] : br[j - HC];
    for (int n0 = blockIdx.x * 2; n0 < N_NODES; n0 += gridDim.x * 2) {
        int n = n0 + group;
        if (n < N_NODES) xrow[group][j] = x[(size_t)n * F_IN + j];
        __syncthreads();
        if (n < N_NODES) {
            float acc = bias;
#pragma unroll 16
            for (int k = 0; k < F_IN; k++) acc += xrow[group][k] * Wb[k][j];
            if (j < HC) xl[(size_t)n * HC + j] = acc;
            else        xr[(size_t)n * HC + (j - HC)] = acc;
        }
        __syncthreads();
    }
}

// fused layer-1: one wave per node, online softmax over its in-edges,
// epilogue = bias + ELU + layer-2 projections (xl2/xr2), h1 never stored.
__global__ void gat1_kernel(const unsigned* __restrict__ row_start, const unsigned* __restrict__ deg,
                            const int* __restrict__ sorted_src, const float* __restrict__ sorted_ea,
                            const float* __restrict__ We1, const float* __restrict__ att1,
                            const float* __restrict__ b1,
                            const float* __restrict__ xl, const float* __restrict__ xr,
                            const float* __restrict__ Wl2, const float* __restrict__ bl2,
                            const float* __restrict__ Wr2, const float* __restrict__ br2,
                            float* __restrict__ xl2, float* __restrict__ xr2) {
    int node = blockIdx.x * (blockDim.x >> 6) + (threadIdx.x >> 6);
    int lane = threadIdx.x & 63;
    if (node >= N_NODES) return;
    unsigned start = row_start[node];
    unsigned cnt   = deg[node];
    float wecol[8];
#pragma unroll
    for (int k = 0; k < 8; k++) wecol[k] = We1[k * HC + lane];
    float attv = att1[lane];
    float xrv  = xr[(size_t)node * HC + lane];

    float m = -INFINITY, den = 0.f, acc = 0.f;

    // software pipeline depth 1
    int s_nxt = sorted_src[start];
    float ea_nxt[8];
#pragma unroll
    for (int k = 0; k < 8; k++) ea_nxt[k] = sorted_ea[(size_t)start * 8 + k];
    float xl_nxt = xl[(size_t)s_nxt * HC + lane];

    for (unsigned j = 0; j < cnt; j++) {
        float xlv = xl_nxt;
        float eac[8];
#pragma unroll
        for (int k = 0; k < 8; k++) eac[k] = ea_nxt[k];
        if (j + 1 < cnt) {
            unsigned idx = start + j + 1;
            s_nxt = sorted_src[idx];
#pragma unroll
            for (int k = 0; k < 8; k++) ea_nxt[k] = sorted_ea[(size_t)idx * 8 + k];
            xl_nxt = xl[(size_t)s_nxt * HC + lane];
        }
        float v = xlv + xrv;
#pragma unroll
        for (int k = 0; k < 8; k++) v += eac[k] * wecol[k];
        v = v > 0.f ? v : NEG * v;
        float prod = v * attv;
        prod += __shfl_xor(prod, 1);
        prod += __shfl_xor(prod, 2);
        prod += __shfl_xor(prod, 4);
        prod += __shfl_xor(prod, 8);   // per-head logit (16-lane groups)
        float mnew  = fmaxf(m, prod);
        float scale = __expf(m - mnew);      // 0 on first iter (m=-inf)
        float p     = __expf(prod - mnew);
        acc = acc * scale + p * xlv;
        den = den * scale + p;
        m = mnew;
    }
    float o = acc / den + b1[lane];
    o = o > 0.f ? o : expm1f(o);         // ELU
    float sl = o * Wl2[lane];
    float sr = o * Wr2[lane];
    for (int off = 32; off; off >>= 1) {
        sl += __shfl_down(sl, off);
        sr += __shfl_down(sr, off);
    }
    if (lane == 0) {
        xl2[node] = sl + bl2[0];
        xr2[node] = sr + br2[0];
    }
}

// fused layer-2: one wave per node, lanes parallel over in-edges
__global__ void gat2_kernel(const unsigned* __restrict__ row_start, const unsigned* __restrict__ deg,
                            const int* __restrict__ sorted_src, const float* __restrict__ sorted_ea,
                            const float* __restrict__ We2, const float* __restrict__ att2,
                            const float* __restrict__ xl2, const float* __restrict__ xr2,
                            const float* __restrict__ b2, float* __restrict__ out) {
    int node = blockIdx.x * (blockDim.x >> 6) + (threadIdx.x >> 6);
    int lane = threadIdx.x & 63;
    if (node >= N_NODES) return;
    unsigned start = row_start[node];
    unsigned cnt   = deg[node];
    float xrv = xr2[node];
    float a2  = att2[0];
    float m = -INFINITY, den = 0.f, num = 0.f;
    for (unsigned base = 0; base < cnt; base += 64) {
        unsigned idx = base + lane;
        float logit = -INFINITY, xv = 0.f;
        if (idx < cnt) {
            int s = sorted_src[start + idx];
            const float* eap = sorted_ea + (size_t)(start + idx) * 8;
            float ee = 0.f;
#pragma unroll
            for (int k = 0; k < 8; k++) ee += eap[k] * We2[k];
            xv = xl2[s];
            float v = xv + xrv + ee;
            v = v > 0.f ? v : NEG * v;
            logit = a2 * v;
        }
        float mm = logit;
        for (int off = 1; off < 64; off <<= 1) mm = fmaxf(mm, __shfl_xor(mm, off));
        float mnew = fmaxf(m, mm);
        float p  = (idx < cnt) ? __expf(logit - mnew) : 0.f;
        float pn = p * xv;
        for (int off = 1; off < 64; off <<= 1) {
            p  += __shfl_xor(p, off);
            pn += __shfl_xor(pn, off);
        }
        float scale = __expf(m - mnew);
        den = den * scale + p;
        num = num * scale + pn;
        m = mnew;
    }
    if (lane == 0) out[node] = num / den + b2[0];
}

extern "C" void kernel_launch(void* const* d_in, const int* in_sizes, int n_in,
                              void* d_out, int out_size, void* d_ws, size_t ws_size,
                              hipStream_t stream) {
    const float* x    = (const float*)d_in[0];
    const int*   ei   = (const int*)d_in[1];
    const float* ea   = (const float*)d_in[2];
    const float* Wl1  = (const float*)d_in[3];
    const float* bl1  = (const float*)d_in[4];
    const float* Wr1  = (const float*)d_in[5];
    const float* br1  = (const float*)d_in[6];
    const float* We1  = (const float*)d_in[7];
    const float* att1 = (const float*)d_in[8];
    const float* b1   = (const float*)d_in[9];
    const float* Wl2  = (const float*)d_in[10];
    const float* bl2  = (const float*)d_in[11];
    const float* Wr2  = (const float*)d_in[12];
    const float* br2  = (const float*)d_in[13];
    const float* We2  = (const float*)d_in[14];
    const float* att2 = (const float*)d_in[15];
    const float* b2   = (const float*)d_in[16];

    const int* src = ei;              // edge_index row 0
    const int* dst = ei + N_EDGES;    // edge_index row 1

    float* W = (float*)d_ws;
    size_t o = 0;
    float*    sum8      = W + o;               o += 8;
    unsigned* deg       = (unsigned*)(W + o);  o += N_NODES;
    unsigned* local_inc = (unsigned*)(W + o);  o += N_NODES;
    unsigned* bsum      = (unsigned*)(W + o);  o += 128;
    unsigned* row_start = (unsigned*)(W + o);  o += N_NODES;
    unsigned* next      = (unsigned*)(W + o);  o += N_NODES;
    int*      ssrc      = (int*)(W + o);       o += N_ITEMS;
    // keep 16B alignment for sorted_ea float4 stores
    o = (o + 3) & ~(size_t)3;
    float*    sea       = W + o;               o += (size_t)N_ITEMS * 8;
    float*    xl1       = W + o;               o += (size_t)N_NODES * HC;
    float*    xr1       = W + o;               o += (size_t)N_NODES * HC;
    float*    xl2       = W + o;               o += N_NODES;
    float*    xr2       = W + o;               o += N_NODES;

    zero_sum8<<<1, 64, 0, stream>>>(sum8);
    init_deg<<<(N_NODES + 255) / 256, 256, 0, stream>>>(deg);
    mean_sum_kernel<<<1024, 256, 0, stream>>>(ea, sum8);
    hist_kernel<<<(N_EDGES + 255) / 256, 256, 0, stream>>>(dst, deg);
    scan1<<<SCAN_NB, SCAN_BS, 0, stream>>>(deg, local_inc, bsum);
    scan2<<<1, 128, 0, stream>>>(bsum);
    scan3<<<(N_NODES + 255) / 256, 256, 0, stream>>>(local_inc, deg, bsum, row_start, next);
    scatter_kernel<<<(N_ITEMS + 255) / 256, 256, 0, stream>>>(src, dst, ea, sum8, next, ssrc, sea);
    gemm1_kernel<<<2048, 256, 0, stream>>>(x, Wl1, bl1, Wr1, br1, xl1, xr1);
    gat1_kernel<<<(N_NODES + 3) / 4, 256, 0, stream>>>(
        row_start, deg, ssrc, sea, We1, att1, b1, xl1, xr1,
        Wl2, bl2, Wr2, br2, xl2, xr2);
    gat2_kernel<<<(N_NODES + 3) / 4, 256, 0, stream>>>(
        row_start, deg, ssrc, sea, We2, att2, xl2, xr2, b2, (float*)d_out);
}

// Round 3
// 669.788 us; speedup vs baseline: 2.5670x; 1.5734x over previous
//
#include <hip/hip_runtime.h>
#include <math.h>

#define N_NODES 100000
#define N_EDGES 1600000
#define N_ITEMS (N_EDGES + N_NODES)   // edges + self loops
#define F_IN 128
#define F_E 8
#define HC 64      // H*C (layer-1 output width)
#define NHEAD 4
#define NEG 0.2f
#define SCAN_BS 1024
#define SCAN_NB ((N_NODES + SCAN_BS - 1) / SCAN_BS)   // 98
#define MS_BLOCKS 1024

__global__ void init_deg(unsigned* __restrict__ deg) {
    int i = blockIdx.x * blockDim.x + threadIdx.x;
    if (i < N_NODES) deg[i] = 1u;   // self loop
}

// per-block partial sums of edge_attr columns (no atomics)
__global__ void mean_sum_kernel(const float* __restrict__ ea, float* __restrict__ partials) {
    __shared__ float sh[4][8];
    float acc[8] = {0.f,0.f,0.f,0.f,0.f,0.f,0.f,0.f};
    int stride = gridDim.x * blockDim.x;
    for (int r = blockIdx.x * blockDim.x + threadIdx.x; r < N_EDGES; r += stride) {
        const float4* p = (const float4*)(ea + (size_t)r * 8);
        float4 a = p[0], b = p[1];
        acc[0] += a.x; acc[1] += a.y; acc[2] += a.z; acc[3] += a.w;
        acc[4] += b.x; acc[5] += b.y; acc[6] += b.z; acc[7] += b.w;
    }
    int wid  = threadIdx.x >> 6;
    int lane = threadIdx.x & 63;
#pragma unroll
    for (int k = 0; k < 8; k++) {
        float v = acc[k];
        for (int off = 32; off; off >>= 1) v += __shfl_down(v, off);
        if (lane == 0) sh[wid][k] = v;
    }
    __syncthreads();
    if (threadIdx.x < 8) {
        float s = sh[0][threadIdx.x] + sh[1][threadIdx.x] + sh[2][threadIdx.x] + sh[3][threadIdx.x];
        partials[blockIdx.x * 8 + threadIdx.x] = s;
    }
}

// one wave: reduce MS_BLOCKS x 8 partials -> sum8
__global__ void reduce_sum8(const float* __restrict__ partials, float* __restrict__ sum8) {
    int lane = threadIdx.x;       // 64 threads
    int c = lane & 7, g = lane >> 3;
    float s = 0.f;
    for (int b = g; b < MS_BLOCKS; b += 8) s += partials[b * 8 + c];
    s += __shfl_xor(s, 8);
    s += __shfl_xor(s, 16);
    s += __shfl_xor(s, 32);
    if (lane < 8) sum8[lane] = s;
}

__global__ void hist_kernel(const int* __restrict__ dst, unsigned* __restrict__ deg) {
    int e = blockIdx.x * blockDim.x + threadIdx.x;
    if (e < N_EDGES) atomicAdd(&deg[dst[e]], 1u);
}

// inclusive block scan of deg -> local_inc; per-block totals -> bsum
__global__ void scan1(const unsigned* __restrict__ deg, unsigned* __restrict__ local_inc,
                      unsigned* __restrict__ bsum) {
    __shared__ unsigned tmp[SCAN_BS];
    int i = blockIdx.x * SCAN_BS + threadIdx.x;
    unsigned v = (i < N_NODES) ? deg[i] : 0u;
    tmp[threadIdx.x] = v;
    __syncthreads();
    for (int off = 1; off < SCAN_BS; off <<= 1) {
        unsigned add = (threadIdx.x >= (unsigned)off) ? tmp[threadIdx.x - off] : 0u;
        __syncthreads();
        tmp[threadIdx.x] += add;
        __syncthreads();
    }
    if (i < N_NODES) local_inc[i] = tmp[threadIdx.x];
    if (threadIdx.x == SCAN_BS - 1) bsum[blockIdx.x] = tmp[threadIdx.x];
}

// exclusive scan of the 98 block sums (single block of 128)
__global__ void scan2(unsigned* __restrict__ bsum) {
    __shared__ unsigned tmp[128];
    int t = threadIdx.x;
    unsigned v = (t < SCAN_NB) ? bsum[t] : 0u;
    tmp[t] = v;
    __syncthreads();
    for (int off = 1; off < 128; off <<= 1) {
        unsigned add = (t >= off) ? tmp[t - off] : 0u;
        __syncthreads();
        tmp[t] += add;
        __syncthreads();
    }
    if (t < SCAN_NB) bsum[t] = tmp[t] - v;   // exclusive
}

__global__ void scan3(const unsigned* __restrict__ local_inc, const unsigned* __restrict__ deg,
                      const unsigned* __restrict__ bsum,
                      unsigned* __restrict__ row_start, unsigned* __restrict__ next) {
    int i = blockIdx.x * blockDim.x + threadIdx.x;
    if (i >= N_NODES) return;
    unsigned v = local_inc[i] - deg[i] + bsum[i / SCAN_BS];
    row_start[i] = v;
    next[i] = v;
}

// scatter edges (+ self loops) into destination-sorted order
__global__ void scatter_kernel(const int* __restrict__ src, const int* __restrict__ dst,
                               const float* __restrict__ ea, const float* __restrict__ sum8,
                               unsigned* __restrict__ next,
                               int* __restrict__ sorted_src, float* __restrict__ sorted_ea) {
    int item = blockIdx.x * blockDim.x + threadIdx.x;
    if (item >= N_ITEMS) return;
    int s, d;
    float4 a, b;
    if (item < N_EDGES) {
        s = src[item]; d = dst[item];
        const float4* p = (const float4*)(ea + (size_t)item * 8);
        a = p[0]; b = p[1];
    } else {
        s = d = item - N_EDGES;
        const float inv = 1.0f / N_EDGES;
        a = make_float4(sum8[0]*inv, sum8[1]*inv, sum8[2]*inv, sum8[3]*inv);
        b = make_float4(sum8[4]*inv, sum8[5]*inv, sum8[6]*inv, sum8[7]*inv);
    }
    unsigned pos = atomicAdd(&next[d], 1u);
    sorted_src[pos] = s;
    float4* q = (float4*)(sorted_ea + (size_t)pos * 8);
    q[0] = a; q[1] = b;
}

// xl = x@Wl + bl ; xr = x@Wr + br    (N x 128) @ (128 x 64)
__global__ void gemm1_kernel(const float* __restrict__ x,
                             const float* __restrict__ Wl, const float* __restrict__ bl,
                             const float* __restrict__ Wr, const float* __restrict__ br,
                             float* __restrict__ xl, float* __restrict__ xr) {
    __shared__ float Wb[F_IN][2 * HC];   // 128x128 f32 = 64 KiB
    __shared__ float xrow[2][F_IN];
    for (int i = threadIdx.x; i < F_IN * HC; i += blockDim.x) {
        int k = i / HC, j = i % HC;
        Wb[k][j]      = Wl[i];
        Wb[k][j + HC] = Wr[i];
    }
    __syncthreads();
    int group = threadIdx.x >> 7;     // 0..1 (node within pair)
    int j     = threadIdx.x & 127;    // combined output column
    float bias = (j < HC) ? bl[j] : br[j - HC];
    for (int n0 = blockIdx.x * 2; n0 < N_NODES; n0 += gridDim.x * 2) {
        int n = n0 + group;
        if (n < N_NODES) xrow[group][j] = x[(size_t)n * F_IN + j];
        __syncthreads();
        if (n < N_NODES) {
            float acc = bias;
#pragma unroll 16
            for (int k = 0; k < F_IN; k++) acc += xrow[group][k] * Wb[k][j];
            if (j < HC) xl[(size_t)n * HC + j] = acc;
            else        xr[(size_t)n * HC + (j - HC)] = acc;
        }
        __syncthreads();
    }
}

// fused layer-1: one wave per node, online softmax over its in-edges,
// epilogue = bias + ELU + layer-2 projections (xl2/xr2), h1 never stored.
__global__ void gat1_kernel(const unsigned* __restrict__ row_start, const unsigned* __restrict__ deg,
                            const int* __restrict__ sorted_src, const float* __restrict__ sorted_ea,
                            const float* __restrict__ We1, const float* __restrict__ att1,
                            const float* __restrict__ b1,
                            const float* __restrict__ xl, const float* __restrict__ xr,
                            const float* __restrict__ Wl2, const float* __restrict__ bl2,
                            const float* __restrict__ Wr2, const float* __restrict__ br2,
                            float* __restrict__ xl2, float* __restrict__ xr2) {
    int node = blockIdx.x * (blockDim.x >> 6) + (threadIdx.x >> 6);
    int lane = threadIdx.x & 63;
    if (node >= N_NODES) return;
    unsigned start = row_start[node];
    unsigned cnt   = deg[node];
    float wecol[8];
#pragma unroll
    for (int k = 0; k < 8; k++) wecol[k] = We1[k * HC + lane];
    float attv = att1[lane];
    float xrv  = xr[(size_t)node * HC + lane];

    float m = -INFINITY, den = 0.f, acc = 0.f;

    // software pipeline depth 1
    int s_nxt = sorted_src[start];
    float ea_nxt[8];
#pragma unroll
    for (int k = 0; k < 8; k++) ea_nxt[k] = sorted_ea[(size_t)start * 8 + k];
    float xl_nxt = xl[(size_t)s_nxt * HC + lane];

    for (unsigned j = 0; j < cnt; j++) {
        float xlv = xl_nxt;
        float eac[8];
#pragma unroll
        for (int k = 0; k < 8; k++) eac[k] = ea_nxt[k];
        if (j + 1 < cnt) {
            unsigned idx = start + j + 1;
            s_nxt = sorted_src[idx];
#pragma unroll
            for (int k = 0; k < 8; k++) ea_nxt[k] = sorted_ea[(size_t)idx * 8 + k];
            xl_nxt = xl[(size_t)s_nxt * HC + lane];
        }
        float v = xlv + xrv;
#pragma unroll
        for (int k = 0; k < 8; k++) v += eac[k] * wecol[k];
        v = v > 0.f ? v : NEG * v;
        float prod = v * attv;
        prod += __shfl_xor(prod, 1);
        prod += __shfl_xor(prod, 2);
        prod += __shfl_xor(prod, 4);
        prod += __shfl_xor(prod, 8);   // per-head logit (16-lane groups)
        float mnew  = fmaxf(m, prod);
        float scale = __expf(m - mnew);      // 0 on first iter (m=-inf)
        float p     = __expf(prod - mnew);
        acc = acc * scale + p * xlv;
        den = den * scale + p;
        m = mnew;
    }
    float o = acc / den + b1[lane];
    o = o > 0.f ? o : expm1f(o);         // ELU
    float sl = o * Wl2[lane];
    float sr = o * Wr2[lane];
    for (int off = 32; off; off >>= 1) {
        sl += __shfl_down(sl, off);
        sr += __shfl_down(sr, off);
    }
    if (lane == 0) {
        xl2[node] = sl + bl2[0];
        xr2[node] = sr + br2[0];
    }
}

// fused layer-2: one wave per node, lanes parallel over in-edges
__global__ void gat2_kernel(const unsigned* __restrict__ row_start, const unsigned* __restrict__ deg,
                            const int* __restrict__ sorted_src, const float* __restrict__ sorted_ea,
                            const float* __restrict__ We2, const float* __restrict__ att2,
                            const float* __restrict__ xl2, const float* __restrict__ xr2,
                            const float* __restrict__ b2, float* __restrict__ out) {
    int node = blockIdx.x * (blockDim.x >> 6) + (threadIdx.x >> 6);
    int lane = threadIdx.x & 63;
    if (node >= N_NODES) return;
    unsigned start = row_start[node];
    unsigned cnt   = deg[node];
    float xrv = xr2[node];
    float a2  = att2[0];
    float m = -INFINITY, den = 0.f, num = 0.f;
    for (unsigned base = 0; base < cnt; base += 64) {
        unsigned idx = base + lane;
        float logit = -INFINITY, xv = 0.f;
        if (idx < cnt) {
            int s = sorted_src[start + idx];
            const float* eap = sorted_ea + (size_t)(start + idx) * 8;
            float ee = 0.f;
#pragma unroll
            for (int k = 0; k < 8; k++) ee += eap[k] * We2[k];
            xv = xl2[s];
            float v = xv + xrv + ee;
            v = v > 0.f ? v : NEG * v;
            logit = a2 * v;
        }
        float mm = logit;
        for (int off = 1; off < 64; off <<= 1) mm = fmaxf(mm, __shfl_xor(mm, off));
        float mnew = fmaxf(m, mm);
        float p  = (idx < cnt) ? __expf(logit - mnew) : 0.f;
        float pn = p * xv;
        for (int off = 1; off < 64; off <<= 1) {
            p  += __shfl_xor(p, off);
            pn += __shfl_xor(pn, off);
        }
        float scale = __expf(m - mnew);
        den = den * scale + p;
        num = num * scale + pn;
        m = mnew;
    }
    if (lane == 0) out[node] = num / den + b2[0];
}

extern "C" void kernel_launch(void* const* d_in, const int* in_sizes, int n_in,
                              void* d_out, int out_size, void* d_ws, size_t ws_size,
                              hipStream_t stream) {
    const float* x    = (const float*)d_in[0];
    const int*   ei   = (const int*)d_in[1];
    const float* ea   = (const float*)d_in[2];
    const float* Wl1  = (const float*)d_in[3];
    const float* bl1  = (const float*)d_in[4];
    const float* Wr1  = (const float*)d_in[5];
    const float* br1  = (const float*)d_in[6];
    const float* We1  = (const float*)d_in[7];
    const float* att1 = (const float*)d_in[8];
    const float* b1   = (const float*)d_in[9];
    const float* Wl2  = (const float*)d_in[10];
    const float* bl2  = (const float*)d_in[11];
    const float* Wr2  = (const float*)d_in[12];
    const float* br2  = (const float*)d_in[13];
    const float* We2  = (const float*)d_in[14];
    const float* att2 = (const float*)d_in[15];
    const float* b2   = (const float*)d_in[16];

    const int* src = ei;              // edge_index row 0
    const int* dst = ei + N_EDGES;    // edge_index row 1

    float* W = (float*)d_ws;
    size_t o = 0;
    float*    sum8      = W + o;               o += 8;
    float*    partials  = W + o;               o += MS_BLOCKS * 8;
    unsigned* deg       = (unsigned*)(W + o);  o += N_NODES;
    unsigned* local_inc = (unsigned*)(W + o);  o += N_NODES;
    unsigned* bsum      = (unsigned*)(W + o);  o += 128;
    unsigned* row_start = (unsigned*)(W + o);  o += N_NODES;
    unsigned* next      = (unsigned*)(W + o);  o += N_NODES;
    int*      ssrc      = (int*)(W + o);       o += N_ITEMS;
    // keep 16B alignment for sorted_ea float4 stores
    o = (o + 3) & ~(size_t)3;
    float*    sea       = W + o;               o += (size_t)N_ITEMS * 8;
    float*    xl1       = W + o;               o += (size_t)N_NODES * HC;
    float*    xr1       = W + o;               o += (size_t)N_NODES * HC;
    float*    xl2       = W + o;               o += N_NODES;
    float*    xr2       = W + o;               o += N_NODES;

    init_deg<<<(N_NODES + 255) / 256, 256, 0, stream>>>(deg);
    mean_sum_kernel<<<MS_BLOCKS, 256, 0, stream>>>(ea, partials);
    reduce_sum8<<<1, 64, 0, stream>>>(partials, sum8);
    hist_kernel<<<(N_EDGES + 255) / 256, 256, 0, stream>>>(dst, deg);
    scan1<<<SCAN_NB, SCAN_BS, 0, stream>>>(deg, local_inc, bsum);
    scan2<<<1, 128, 0, stream>>>(bsum);
    scan3<<<(N_NODES + 255) / 256, 256, 0, stream>>>(local_inc, deg, bsum, row_start, next);
    scatter_kernel<<<(N_ITEMS + 255) / 256, 256, 0, stream>>>(src, dst, ea, sum8, next, ssrc, sea);
    gemm1_kernel<<<2048, 256, 0, stream>>>(x, Wl1, bl1, Wr1, br1, xl1, xr1);
    gat1_kernel<<<(N_NODES + 3) / 4, 256, 0, stream>>>(
        row_start, deg, ssrc, sea, We1, att1, b1, xl1, xr1,
        Wl2, bl2, Wr2, br2, xl2, xr2);
    gat2_kernel<<<(N_NODES + 3) / 4, 256, 0, stream>>>(
        row_start, deg, ssrc, sea, We2, att2, xl2, xr2, b2, (float*)d_out);
}

// Round 4
// 455.401 us; speedup vs baseline: 3.7755x; 1.4708x over previous
//
#include <hip/hip_runtime.h>
#include <math.h>

#define N_NODES 100000
#define N_EDGES 1600000
#define N_ITEMS (N_EDGES + N_NODES)   // edges + self loops
#define F_IN 128
#define F_E 8
#define HC 64      // H*C (layer-1 output width)
#define NHEAD 4
#define NEG 0.2f
#define SCAN_BS 1024
#define SCAN_NB ((N_NODES + SCAN_BS - 1) / SCAN_BS)   // 98
#define MS_BLOCKS 1024
#define NEG_BIG (-3.0e38f)

__global__ void init_deg(unsigned* __restrict__ deg) {
    int i = blockIdx.x * blockDim.x + threadIdx.x;
    if (i < N_NODES) deg[i] = 1u;   // self loop
}

// per-block partial sums of edge_attr columns (no atomics)
__global__ void mean_sum_kernel(const float* __restrict__ ea, float* __restrict__ partials) {
    __shared__ float sh[4][8];
    float acc[8] = {0.f,0.f,0.f,0.f,0.f,0.f,0.f,0.f};
    int stride = gridDim.x * blockDim.x;
    for (int r = blockIdx.x * blockDim.x + threadIdx.x; r < N_EDGES; r += stride) {
        const float4* p = (const float4*)(ea + (size_t)r * 8);
        float4 a = p[0], b = p[1];
        acc[0] += a.x; acc[1] += a.y; acc[2] += a.z; acc[3] += a.w;
        acc[4] += b.x; acc[5] += b.y; acc[6] += b.z; acc[7] += b.w;
    }
    int wid  = threadIdx.x >> 6;
    int lane = threadIdx.x & 63;
#pragma unroll
    for (int k = 0; k < 8; k++) {
        float v = acc[k];
        for (int off = 32; off; off >>= 1) v += __shfl_down(v, off);
        if (lane == 0) sh[wid][k] = v;
    }
    __syncthreads();
    if (threadIdx.x < 8) {
        float s = sh[0][threadIdx.x] + sh[1][threadIdx.x] + sh[2][threadIdx.x] + sh[3][threadIdx.x];
        partials[blockIdx.x * 8 + threadIdx.x] = s;
    }
}

// one wave: reduce MS_BLOCKS x 8 partials -> sum8
__global__ void reduce_sum8(const float* __restrict__ partials, float* __restrict__ sum8) {
    int lane = threadIdx.x;       // 64 threads
    int c = lane & 7, g = lane >> 3;
    float s = 0.f;
    for (int b = g; b < MS_BLOCKS; b += 8) s += partials[b * 8 + c];
    s += __shfl_xor(s, 8);
    s += __shfl_xor(s, 16);
    s += __shfl_xor(s, 32);
    if (lane < 8) sum8[lane] = s;
}

__global__ void hist_kernel(const int* __restrict__ dst, unsigned* __restrict__ deg) {
    int e = blockIdx.x * blockDim.x + threadIdx.x;
    if (e < N_EDGES) atomicAdd(&deg[dst[e]], 1u);
}

// inclusive block scan of deg -> local_inc; per-block totals -> bsum
__global__ void scan1(const unsigned* __restrict__ deg, unsigned* __restrict__ local_inc,
                      unsigned* __restrict__ bsum) {
    __shared__ unsigned tmp[SCAN_BS];
    int i = blockIdx.x * SCAN_BS + threadIdx.x;
    unsigned v = (i < N_NODES) ? deg[i] : 0u;
    tmp[threadIdx.x] = v;
    __syncthreads();
    for (int off = 1; off < SCAN_BS; off <<= 1) {
        unsigned add = (threadIdx.x >= (unsigned)off) ? tmp[threadIdx.x - off] : 0u;
        __syncthreads();
        tmp[threadIdx.x] += add;
        __syncthreads();
    }
    if (i < N_NODES) local_inc[i] = tmp[threadIdx.x];
    if (threadIdx.x == SCAN_BS - 1) bsum[blockIdx.x] = tmp[threadIdx.x];
}

// exclusive scan of the 98 block sums (single block of 128)
__global__ void scan2(unsigned* __restrict__ bsum) {
    __shared__ unsigned tmp[128];
    int t = threadIdx.x;
    unsigned v = (t < SCAN_NB) ? bsum[t] : 0u;
    tmp[t] = v;
    __syncthreads();
    for (int off = 1; off < 128; off <<= 1) {
        unsigned add = (t >= off) ? tmp[t - off] : 0u;
        __syncthreads();
        tmp[t] += add;
        __syncthreads();
    }
    if (t < SCAN_NB) bsum[t] = tmp[t] - v;   // exclusive
}

__global__ void scan3(const unsigned* __restrict__ local_inc, const unsigned* __restrict__ deg,
                      const unsigned* __restrict__ bsum,
                      unsigned* __restrict__ row_start, unsigned* __restrict__ next) {
    int i = blockIdx.x * blockDim.x + threadIdx.x;
    if (i >= N_NODES) return;
    unsigned v = local_inc[i] - deg[i] + bsum[i / SCAN_BS];
    row_start[i] = v;
    next[i] = v;
}

// scatter edges (+ self loops) into destination-sorted order
__global__ void scatter_kernel(const int* __restrict__ src, const int* __restrict__ dst,
                               const float* __restrict__ ea, const float* __restrict__ sum8,
                               unsigned* __restrict__ next,
                               int* __restrict__ sorted_src, float* __restrict__ sorted_ea) {
    int item = blockIdx.x * blockDim.x + threadIdx.x;
    if (item >= N_ITEMS) return;
    int s, d;
    float4 a, b;
    if (item < N_EDGES) {
        s = src[item]; d = dst[item];
        const float4* p = (const float4*)(ea + (size_t)item * 8);
        a = p[0]; b = p[1];
    } else {
        s = d = item - N_EDGES;
        const float inv = 1.0f / N_EDGES;
        a = make_float4(sum8[0]*inv, sum8[1]*inv, sum8[2]*inv, sum8[3]*inv);
        b = make_float4(sum8[4]*inv, sum8[5]*inv, sum8[6]*inv, sum8[7]*inv);
    }
    unsigned pos = atomicAdd(&next[d], 1u);
    sorted_src[pos] = s;
    float4* q = (float4*)(sorted_ea + (size_t)pos * 8);
    q[0] = a; q[1] = b;
}

// xl = x@Wl + bl ; xr = x@Wr + br    (N x 128) @ (128 x 64)
// 32-node tile; x transposed in LDS (pad 36 for aligned b128 reads);
// thread computes 4 nodes x 4 cols; W streamed from global (L2-resident).
__global__ __launch_bounds__(256) void gemm1_kernel(
        const float* __restrict__ x,
        const float* __restrict__ Wl, const float* __restrict__ bl,
        const float* __restrict__ Wr, const float* __restrict__ br,
        float* __restrict__ xl, float* __restrict__ xr) {
    __shared__ float xs_t[F_IN][36];      // [k][node], padded -> 18 KiB
    int t = threadIdx.x & 31;             // col-quad: combined cols 4t..4t+3
    int g = threadIdx.x >> 5;             // node-quad: nodes 4g..4g+3 of the tile
    const float* Wsel = (t < 16) ? Wl : Wr;
    const float* bsel = (t < 16) ? bl : br;
    int jc = (t < 16) ? 4 * t : 4 * t - HC;
    float4 bias = *(const float4*)(bsel + jc);
    float* dstp = (t < 16) ? xl : xr;

    int n0 = blockIdx.x * 32;             // N_NODES = 32*3125 exactly
    // load 32 rows of x, write transposed to LDS
    int row = threadIdx.x >> 3;           // 0..31
    int cq  = threadIdx.x & 7;            // col chunk
#pragma unroll
    for (int r = 0; r < 4; r++) {
        int c = cq * 4 + r * 32;
        float4 v = *(const float4*)(x + (size_t)(n0 + row) * F_IN + c);
        xs_t[c + 0][row] = v.x;
        xs_t[c + 1][row] = v.y;
        xs_t[c + 2][row] = v.z;
        xs_t[c + 3][row] = v.w;
    }
    __syncthreads();
    int nb = g * 4;
    float4 a0 = bias, a1 = bias, a2 = bias, a3 = bias;
#pragma unroll 4
    for (int k = 0; k < F_IN; k++) {
        float4 w  = *(const float4*)(Wsel + k * HC + jc);
        float4 xv = *(const float4*)&xs_t[k][nb];
        a0.x += w.x * xv.x; a0.y += w.y * xv.x; a0.z += w.z * xv.x; a0.w += w.w * xv.x;
        a1.x += w.x * xv.y; a1.y += w.y * xv.y; a1.z += w.z * xv.y; a1.w += w.w * xv.y;
        a2.x += w.x * xv.z; a2.y += w.y * xv.z; a2.z += w.z * xv.z; a2.w += w.w * xv.z;
        a3.x += w.x * xv.w; a3.y += w.y * xv.w; a3.z += w.z * xv.w; a3.w += w.w * xv.w;
    }
    *(float4*)(dstp + (size_t)(n0 + nb + 0) * HC + jc) = a0;
    *(float4*)(dstp + (size_t)(n0 + nb + 1) * HC + jc) = a1;
    *(float4*)(dstp + (size_t)(n0 + nb + 2) * HC + jc) = a2;
    *(float4*)(dstp + (size_t)(n0 + nb + 3) * HC + jc) = a3;
}

// fused layer-1: one wave per node, 4 edges per iteration (16 lanes/edge,
// each lane owns 4 channels). 4 parallel online-softmax streams, merged at end.
// Epilogue: bias + ELU + layer-2 projections. h1 never stored.
__global__ void gat1_kernel(const unsigned* __restrict__ row_start, const unsigned* __restrict__ deg,
                            const int* __restrict__ ssrc, const float* __restrict__ sea,
                            const float* __restrict__ We1, const float* __restrict__ att1,
                            const float* __restrict__ b1,
                            const float* __restrict__ xl, const float* __restrict__ xr,
                            const float* __restrict__ Wl2, const float* __restrict__ bl2,
                            const float* __restrict__ Wr2, const float* __restrict__ br2,
                            float* __restrict__ xl2, float* __restrict__ xr2) {
    int node = blockIdx.x * (blockDim.x >> 6) + (threadIdx.x >> 6);
    int lane = threadIdx.x & 63;
    if (node >= N_NODES) return;
    int g  = lane >> 4;          // edge sub-stream 0..3
    int cl = lane & 15;          // channel-slot: channels 4cl..4cl+3
    unsigned start = row_start[node];
    unsigned cnt   = deg[node];

    float4 we[8];
#pragma unroll
    for (int k = 0; k < 8; k++) we[k] = *(const float4*)(We1 + k * HC + 4 * cl);
    float4 attv = *(const float4*)(att1 + 4 * cl);
    float4 xrv  = *(const float4*)(xr + (size_t)node * HC + 4 * cl);

    float m = NEG_BIG, den = 0.f;
    float4 acc = make_float4(0.f, 0.f, 0.f, 0.f);

    // prefetch (depth 1)
    bool valid_n = ((unsigned)g < cnt);
    unsigned safe = valid_n ? start + g : start;
    int s_n = ssrc[safe];
    float4 ea0_n = *(const float4*)(sea + (size_t)safe * 8);
    float4 ea1_n = *(const float4*)(sea + (size_t)safe * 8 + 4);
    float4 xl_n  = *(const float4*)(xl + (size_t)s_n * HC + 4 * cl);

    for (unsigned j = 0; j < cnt; j += 4) {
        bool valid = valid_n;
        float4 ea0 = ea0_n, ea1 = ea1_n, xlv = xl_n;
        unsigned jn = j + 4;
        if (jn < cnt) {
            valid_n = (jn + g < cnt);
            unsigned sf = valid_n ? start + jn + g : start;
            s_n = ssrc[sf];
            ea0_n = *(const float4*)(sea + (size_t)sf * 8);
            ea1_n = *(const float4*)(sea + (size_t)sf * 8 + 4);
            xl_n  = *(const float4*)(xl + (size_t)s_n * HC + 4 * cl);
        }
        float4 v;
        v.x = xlv.x + xrv.x + ea0.x*we[0].x + ea0.y*we[1].x + ea0.z*we[2].x + ea0.w*we[3].x
                            + ea1.x*we[4].x + ea1.y*we[5].x + ea1.z*we[6].x + ea1.w*we[7].x;
        v.y = xlv.y + xrv.y + ea0.x*we[0].y + ea0.y*we[1].y + ea0.z*we[2].y + ea0.w*we[3].y
                            + ea1.x*we[4].y + ea1.y*we[5].y + ea1.z*we[6].y + ea1.w*we[7].y;
        v.z = xlv.z + xrv.z + ea0.x*we[0].z + ea0.y*we[1].z + ea0.z*we[2].z + ea0.w*we[3].z
                            + ea1.x*we[4].z + ea1.y*we[5].z + ea1.z*we[6].z + ea1.w*we[7].z;
        v.w = xlv.w + xrv.w + ea0.x*we[0].w + ea0.y*we[1].w + ea0.z*we[2].w + ea0.w*we[3].w
                            + ea1.x*we[4].w + ea1.y*we[5].w + ea1.z*we[6].w + ea1.w*we[7].w;
        v.x = v.x > 0.f ? v.x : NEG * v.x;
        v.y = v.y > 0.f ? v.y : NEG * v.y;
        v.z = v.z > 0.f ? v.z : NEG * v.z;
        v.w = v.w > 0.f ? v.w : NEG * v.w;
        float prod = v.x*attv.x + v.y*attv.y + v.z*attv.z + v.w*attv.w;
        prod += __shfl_xor(prod, 1);
        prod += __shfl_xor(prod, 2);      // per-head logit in each 4-lane cluster
        float logit = valid ? prod : NEG_BIG;
        float mnew  = fmaxf(m, logit);
        float scale = __expf(m - mnew);
        float p     = valid ? __expf(logit - mnew) : 0.f;
        den   = den   * scale + p;
        acc.x = acc.x * scale + p * xlv.x;
        acc.y = acc.y * scale + p * xlv.y;
        acc.z = acc.z * scale + p * xlv.z;
        acc.w = acc.w * scale + p * xlv.w;
        m = mnew;
    }
    // merge the 4 sub-streams (lanes differing in bits 4,5)
    float M = m;
    M = fmaxf(M, __shfl_xor(M, 16));
    M = fmaxf(M, __shfl_xor(M, 32));
    float gs = __expf(m - M);
    den *= gs; acc.x *= gs; acc.y *= gs; acc.z *= gs; acc.w *= gs;
    den   += __shfl_xor(den, 16);   den   += __shfl_xor(den, 32);
    acc.x += __shfl_xor(acc.x, 16); acc.x += __shfl_xor(acc.x, 32);
    acc.y += __shfl_xor(acc.y, 16); acc.y += __shfl_xor(acc.y, 32);
    acc.z += __shfl_xor(acc.z, 16); acc.z += __shfl_xor(acc.z, 32);
    acc.w += __shfl_xor(acc.w, 16); acc.w += __shfl_xor(acc.w, 32);

    float4 b1v  = *(const float4*)(b1 + 4 * cl);
    float4 wl2v = *(const float4*)(Wl2 + 4 * cl);
    float4 wr2v = *(const float4*)(Wr2 + 4 * cl);
    float inv_den = 1.f / den;
    float4 o;
    o.x = acc.x * inv_den + b1v.x;
    o.y = acc.y * inv_den + b1v.y;
    o.z = acc.z * inv_den + b1v.z;
    o.w = acc.w * inv_den + b1v.w;
    o.x = o.x > 0.f ? o.x : expm1f(o.x);
    o.y = o.y > 0.f ? o.y : expm1f(o.y);
    o.z = o.z > 0.f ? o.z : expm1f(o.z);
    o.w = o.w > 0.f ? o.w : expm1f(o.w);
    float sl = o.x*wl2v.x + o.y*wl2v.y + o.z*wl2v.z + o.w*wl2v.w;
    float sr = o.x*wr2v.x + o.y*wr2v.y + o.z*wr2v.z + o.w*wr2v.w;
#pragma unroll
    for (int off = 1; off <= 8; off <<= 1) {
        sl += __shfl_xor(sl, off);
        sr += __shfl_xor(sr, off);
    }
    if (lane == 0) {
        xl2[node] = sl + bl2[0];
        xr2[node] = sr + br2[0];
    }
}

// fused layer-2: one wave per node, lanes parallel over in-edges
__global__ void gat2_kernel(const unsigned* __restrict__ row_start, const unsigned* __restrict__ deg,
                            const int* __restrict__ sorted_src, const float* __restrict__ sorted_ea,
                            const float* __restrict__ We2, const float* __restrict__ att2,
                            const float* __restrict__ xl2, const float* __restrict__ xr2,
                            const float* __restrict__ b2, float* __restrict__ out) {
    int node = blockIdx.x * (blockDim.x >> 6) + (threadIdx.x >> 6);
    int lane = threadIdx.x & 63;
    if (node >= N_NODES) return;
    unsigned start = row_start[node];
    unsigned cnt   = deg[node];
    float xrv = xr2[node];
    float a2  = att2[0];
    float m = -INFINITY, den = 0.f, num = 0.f;
    for (unsigned base = 0; base < cnt; base += 64) {
        unsigned idx = base + lane;
        float logit = -INFINITY, xv = 0.f;
        if (idx < cnt) {
            int s = sorted_src[start + idx];
            const float* eap = sorted_ea + (size_t)(start + idx) * 8;
            float ee = 0.f;
#pragma unroll
            for (int k = 0; k < 8; k++) ee += eap[k] * We2[k];
            xv = xl2[s];
            float v = xv + xrv + ee;
            v = v > 0.f ? v : NEG * v;
            logit = a2 * v;
        }
        float mm = logit;
        for (int off = 1; off < 64; off <<= 1) mm = fmaxf(mm, __shfl_xor(mm, off));
        float mnew = fmaxf(m, mm);
        float p  = (idx < cnt) ? __expf(logit - mnew) : 0.f;
        float pn = p * xv;
        for (int off = 1; off < 64; off <<= 1) {
            p  += __shfl_xor(p, off);
            pn += __shfl_xor(pn, off);
        }
        float scale = __expf(m - mnew);
        den = den * scale + p;
        num = num * scale + pn;
        m = mnew;
    }
    if (lane == 0) out[node] = num / den + b2[0];
}

extern "C" void kernel_launch(void* const* d_in, const int* in_sizes, int n_in,
                              void* d_out, int out_size, void* d_ws, size_t ws_size,
                              hipStream_t stream) {
    const float* x    = (const float*)d_in[0];
    const int*   ei   = (const int*)d_in[1];
    const float* ea   = (const float*)d_in[2];
    const float* Wl1  = (const float*)d_in[3];
    const float* bl1  = (const float*)d_in[4];
    const float* Wr1  = (const float*)d_in[5];
    const float* br1  = (const float*)d_in[6];
    const float* We1  = (const float*)d_in[7];
    const float* att1 = (const float*)d_in[8];
    const float* b1   = (const float*)d_in[9];
    const float* Wl2  = (const float*)d_in[10];
    const float* bl2  = (const float*)d_in[11];
    const float* Wr2  = (const float*)d_in[12];
    const float* br2  = (const float*)d_in[13];
    const float* We2  = (const float*)d_in[14];
    const float* att2 = (const float*)d_in[15];
    const float* b2   = (const float*)d_in[16];

    const int* src = ei;              // edge_index row 0
    const int* dst = ei + N_EDGES;    // edge_index row 1

    float* W = (float*)d_ws;
    size_t o = 0;
    float*    sum8      = W + o;               o += 8;
    float*    partials  = W + o;               o += MS_BLOCKS * 8;
    unsigned* deg       = (unsigned*)(W + o);  o += N_NODES;
    unsigned* local_inc = (unsigned*)(W + o);  o += N_NODES;
    unsigned* bsum      = (unsigned*)(W + o);  o += 128;
    unsigned* row_start = (unsigned*)(W + o);  o += N_NODES;
    unsigned* next      = (unsigned*)(W + o);  o += N_NODES;
    int*      ssrc      = (int*)(W + o);       o += N_ITEMS;
    o = (o + 3) & ~(size_t)3;
    float*    sea       = W + o;               o += (size_t)N_ITEMS * 8;
    float*    xl1       = W + o;               o += (size_t)N_NODES * HC;
    float*    xr1       = W + o;               o += (size_t)N_NODES * HC;
    float*    xl2       = W + o;               o += N_NODES;
    float*    xr2       = W + o;               o += N_NODES;

    init_deg<<<(N_NODES + 255) / 256, 256, 0, stream>>>(deg);
    mean_sum_kernel<<<MS_BLOCKS, 256, 0, stream>>>(ea, partials);
    reduce_sum8<<<1, 64, 0, stream>>>(partials, sum8);
    hist_kernel<<<(N_EDGES + 255) / 256, 256, 0, stream>>>(dst, deg);
    scan1<<<SCAN_NB, SCAN_BS, 0, stream>>>(deg, local_inc, bsum);
    scan2<<<1, 128, 0, stream>>>(bsum);
    scan3<<<(N_NODES + 255) / 256, 256, 0, stream>>>(local_inc, deg, bsum, row_start, next);
    scatter_kernel<<<(N_ITEMS + 255) / 256, 256, 0, stream>>>(src, dst, ea, sum8, next, ssrc, sea);
    gemm1_kernel<<<N_NODES / 32, 256, 0, stream>>>(x, Wl1, bl1, Wr1, br1, xl1, xr1);
    gat1_kernel<<<(N_NODES + 3) / 4, 256, 0, stream>>>(
        row_start, deg, ssrc, sea, We1, att1, b1, xl1, xr1,
        Wl2, bl2, Wr2, br2, xl2, xr2);
    gat2_kernel<<<(N_NODES + 3) / 4, 256, 0, stream>>>(
        row_start, deg, ssrc, sea, We2, att2, xl2, xr2, b2, (float*)d_out);
}

// Round 5
// 435.316 us; speedup vs baseline: 3.9497x; 1.0461x over previous
//
#include <hip/hip_runtime.h>
#include <math.h>

#define N_NODES 100000
#define N_EDGES 1600000
#define N_ITEMS (N_EDGES + N_NODES)   // edges + self loops
#define F_IN 128
#define F_E 8
#define HC 64      // H*C (layer-1 output width)
#define NHEAD 4
#define NEG 0.2f
#define SCAN_BS 1024
#define SCAN_NB ((N_NODES + SCAN_BS - 1) / SCAN_BS)   // 98
#define MS_BLOCKS 1024
#define NEG_BIG (-3.0e38f)

// per-block partial sums of edge_attr columns (no atomics); also inits deg=1
__global__ void mean_sum_kernel(const float* __restrict__ ea, float* __restrict__ partials,
                                unsigned* __restrict__ deg) {
    __shared__ float sh[4][8];
    int stride = gridDim.x * blockDim.x;
    for (int i = blockIdx.x * blockDim.x + threadIdx.x; i < N_NODES; i += stride)
        deg[i] = 1u;   // self loop
    float acc[8] = {0.f,0.f,0.f,0.f,0.f,0.f,0.f,0.f};
    for (int r = blockIdx.x * blockDim.x + threadIdx.x; r < N_EDGES; r += stride) {
        const float4* p = (const float4*)(ea + (size_t)r * 8);
        float4 a = p[0], b = p[1];
        acc[0] += a.x; acc[1] += a.y; acc[2] += a.z; acc[3] += a.w;
        acc[4] += b.x; acc[5] += b.y; acc[6] += b.z; acc[7] += b.w;
    }
    int wid  = threadIdx.x >> 6;
    int lane = threadIdx.x & 63;
#pragma unroll
    for (int k = 0; k < 8; k++) {
        float v = acc[k];
        for (int off = 32; off; off >>= 1) v += __shfl_down(v, off);
        if (lane == 0) sh[wid][k] = v;
    }
    __syncthreads();
    if (threadIdx.x < 8) {
        float s = sh[0][threadIdx.x] + sh[1][threadIdx.x] + sh[2][threadIdx.x] + sh[3][threadIdx.x];
        partials[blockIdx.x * 8 + threadIdx.x] = s;
    }
}

// one wave: reduce MS_BLOCKS x 8 partials -> sum8
__global__ void reduce_sum8(const float* __restrict__ partials, float* __restrict__ sum8) {
    int lane = threadIdx.x;       // 64 threads
    int c = lane & 7, g = lane >> 3;
    float s = 0.f;
    for (int b = g; b < MS_BLOCKS; b += 8) s += partials[b * 8 + c];
    s += __shfl_xor(s, 8);
    s += __shfl_xor(s, 16);
    s += __shfl_xor(s, 32);
    if (lane < 8) sum8[lane] = s;
}

__global__ void hist_kernel(const int* __restrict__ dst, unsigned* __restrict__ deg) {
    int e = blockIdx.x * blockDim.x + threadIdx.x;
    if (e < N_EDGES) atomicAdd(&deg[dst[e]], 1u);
}

// inclusive block scan of deg -> local_inc; per-block totals -> bsum
__global__ void scan1(const unsigned* __restrict__ deg, unsigned* __restrict__ local_inc,
                      unsigned* __restrict__ bsum) {
    __shared__ unsigned tmp[SCAN_BS];
    int i = blockIdx.x * SCAN_BS + threadIdx.x;
    unsigned v = (i < N_NODES) ? deg[i] : 0u;
    tmp[threadIdx.x] = v;
    __syncthreads();
    for (int off = 1; off < SCAN_BS; off <<= 1) {
        unsigned add = (threadIdx.x >= (unsigned)off) ? tmp[threadIdx.x - off] : 0u;
        __syncthreads();
        tmp[threadIdx.x] += add;
        __syncthreads();
    }
    if (i < N_NODES) local_inc[i] = tmp[threadIdx.x];
    if (threadIdx.x == SCAN_BS - 1) bsum[blockIdx.x] = tmp[threadIdx.x];
}

// exclusive scan of the 98 block sums (single block of 128)
__global__ void scan2(unsigned* __restrict__ bsum) {
    __shared__ unsigned tmp[128];
    int t = threadIdx.x;
    unsigned v = (t < SCAN_NB) ? bsum[t] : 0u;
    tmp[t] = v;
    __syncthreads();
    for (int off = 1; off < 128; off <<= 1) {
        unsigned add = (t >= off) ? tmp[t - off] : 0u;
        __syncthreads();
        tmp[t] += add;
        __syncthreads();
    }
    if (t < SCAN_NB) bsum[t] = tmp[t] - v;   // exclusive
}

__global__ void scan3(const unsigned* __restrict__ local_inc, const unsigned* __restrict__ deg,
                      const unsigned* __restrict__ bsum,
                      unsigned* __restrict__ row_start, unsigned* __restrict__ next) {
    int i = blockIdx.x * blockDim.x + threadIdx.x;
    if (i >= N_NODES) return;
    unsigned v = local_inc[i] - deg[i] + bsum[i / SCAN_BS];
    row_start[i] = v;
    next[i] = v;
}

// scatter edges (+ self loops) into destination-sorted order; also precompute
// see2 = ea @ We2 (scalar per item) for layer 2.
__global__ void scatter_kernel(const int* __restrict__ src, const int* __restrict__ dst,
                               const float* __restrict__ ea, const float* __restrict__ sum8,
                               const float* __restrict__ We2,
                               unsigned* __restrict__ next,
                               int* __restrict__ sorted_src, float* __restrict__ sorted_ea,
                               float* __restrict__ see2) {
    int item = blockIdx.x * blockDim.x + threadIdx.x;
    if (item >= N_ITEMS) return;
    int s, d;
    float4 a, b;
    if (item < N_EDGES) {
        s = src[item]; d = dst[item];
        const float4* p = (const float4*)(ea + (size_t)item * 8);
        a = p[0]; b = p[1];
    } else {
        s = d = item - N_EDGES;
        const float inv = 1.0f / N_EDGES;
        a = make_float4(sum8[0]*inv, sum8[1]*inv, sum8[2]*inv, sum8[3]*inv);
        b = make_float4(sum8[4]*inv, sum8[5]*inv, sum8[6]*inv, sum8[7]*inv);
    }
    float ee2 = a.x*We2[0] + a.y*We2[1] + a.z*We2[2] + a.w*We2[3]
              + b.x*We2[4] + b.y*We2[5] + b.z*We2[6] + b.w*We2[7];
    unsigned pos = atomicAdd(&next[d], 1u);
    sorted_src[pos] = s;
    see2[pos] = ee2;
    float4* q = (float4*)(sorted_ea + (size_t)pos * 8);
    q[0] = a; q[1] = b;
}

// xl = x@Wl + bl ; xr = x@Wr + br    (N x 128) @ (128 x 64)
__global__ __launch_bounds__(256) void gemm1_kernel(
        const float* __restrict__ x,
        const float* __restrict__ Wl, const float* __restrict__ bl,
        const float* __restrict__ Wr, const float* __restrict__ br,
        float* __restrict__ xl, float* __restrict__ xr) {
    __shared__ float xs_t[F_IN][36];      // [k][node], padded -> 18 KiB
    int t = threadIdx.x & 31;             // col-quad: combined cols 4t..4t+3
    int g = threadIdx.x >> 5;             // node-quad: nodes 4g..4g+3 of the tile
    const float* Wsel = (t < 16) ? Wl : Wr;
    const float* bsel = (t < 16) ? bl : br;
    int jc = (t < 16) ? 4 * t : 4 * t - HC;
    float4 bias = *(const float4*)(bsel + jc);
    float* dstp = (t < 16) ? xl : xr;

    int n0 = blockIdx.x * 32;             // N_NODES = 32*3125 exactly
    int row = threadIdx.x >> 3;           // 0..31
    int cq  = threadIdx.x & 7;            // col chunk
#pragma unroll
    for (int r = 0; r < 4; r++) {
        int c = cq * 4 + r * 32;
        float4 v = *(const float4*)(x + (size_t)(n0 + row) * F_IN + c);
        xs_t[c + 0][row] = v.x;
        xs_t[c + 1][row] = v.y;
        xs_t[c + 2][row] = v.z;
        xs_t[c + 3][row] = v.w;
    }
    __syncthreads();
    int nb = g * 4;
    float4 a0 = bias, a1 = bias, a2 = bias, a3 = bias;
#pragma unroll 4
    for (int k = 0; k < F_IN; k++) {
        float4 w  = *(const float4*)(Wsel + k * HC + jc);
        float4 xv = *(const float4*)&xs_t[k][nb];
        a0.x += w.x * xv.x; a0.y += w.y * xv.x; a0.z += w.z * xv.x; a0.w += w.w * xv.x;
        a1.x += w.x * xv.y; a1.y += w.y * xv.y; a1.z += w.z * xv.y; a1.w += w.w * xv.y;
        a2.x += w.x * xv.z; a2.y += w.y * xv.z; a2.z += w.z * xv.z; a2.w += w.w * xv.z;
        a3.x += w.x * xv.w; a3.y += w.y * xv.w; a3.z += w.z * xv.w; a3.w += w.w * xv.w;
    }
    *(float4*)(dstp + (size_t)(n0 + nb + 0) * HC + jc) = a0;
    *(float4*)(dstp + (size_t)(n0 + nb + 1) * HC + jc) = a1;
    *(float4*)(dstp + (size_t)(n0 + nb + 2) * HC + jc) = a2;
    *(float4*)(dstp + (size_t)(n0 + nb + 3) * HC + jc) = a3;
}

__device__ __forceinline__ void load_edge(const int* __restrict__ ssrc,
                                          const float* __restrict__ sea,
                                          const float* __restrict__ xl,
                                          unsigned start, unsigned cnt, unsigned idx, int cl,
                                          bool& valid, float4& e0, float4& e1, float4& xv) {
    valid = (idx < cnt);
    unsigned sf = valid ? start + idx : start;
    int s = ssrc[sf];
    e0 = *(const float4*)(sea + (size_t)sf * 8);
    e1 = *(const float4*)(sea + (size_t)sf * 8 + 4);
    xv = *(const float4*)(xl + (size_t)s * HC + 4 * cl);
}

__device__ __forceinline__ void edge_update(const float4* __restrict__ we,
                                            const float4& attv, const float4& xrv,
                                            bool valid, const float4& ea0, const float4& ea1,
                                            const float4& xlv,
                                            float& m, float& den, float4& acc) {
    float4 v;
    v.x = xlv.x + xrv.x + ea0.x*we[0].x + ea0.y*we[1].x + ea0.z*we[2].x + ea0.w*we[3].x
                        + ea1.x*we[4].x + ea1.y*we[5].x + ea1.z*we[6].x + ea1.w*we[7].x;
    v.y = xlv.y + xrv.y + ea0.x*we[0].y + ea0.y*we[1].y + ea0.z*we[2].y + ea0.w*we[3].y
                        + ea1.x*we[4].y + ea1.y*we[5].y + ea1.z*we[6].y + ea1.w*we[7].y;
    v.z = xlv.z + xrv.z + ea0.x*we[0].z + ea0.y*we[1].z + ea0.z*we[2].z + ea0.w*we[3].z
                        + ea1.x*we[4].z + ea1.y*we[5].z + ea1.z*we[6].z + ea1.w*we[7].z;
    v.w = xlv.w + xrv.w + ea0.x*we[0].w + ea0.y*we[1].w + ea0.z*we[2].w + ea0.w*we[3].w
                        + ea1.x*we[4].w + ea1.y*we[5].w + ea1.z*we[6].w + ea1.w*we[7].w;
    v.x = v.x > 0.f ? v.x : NEG * v.x;
    v.y = v.y > 0.f ? v.y : NEG * v.y;
    v.z = v.z > 0.f ? v.z : NEG * v.z;
    v.w = v.w > 0.f ? v.w : NEG * v.w;
    float prod = v.x*attv.x + v.y*attv.y + v.z*attv.z + v.w*attv.w;
    prod += __shfl_xor(prod, 1);
    prod += __shfl_xor(prod, 2);      // per-head logit in each 4-lane cluster
    float logit = valid ? prod : NEG_BIG;
    float mnew  = fmaxf(m, logit);
    float scale = __expf(m - mnew);
    float p     = valid ? __expf(logit - mnew) : 0.f;
    den   = den   * scale + p;
    acc.x = acc.x * scale + p * xlv.x;
    acc.y = acc.y * scale + p * xlv.y;
    acc.z = acc.z * scale + p * xlv.z;
    acc.w = acc.w * scale + p * xlv.w;
    m = mnew;
}

// fused layer-1: one wave per node, 8 edges per iteration as TWO independent
// online-softmax streams (ILP to hide gather latency). 16 lanes/edge, 4 ch/lane.
__global__ void gat1_kernel(const unsigned* __restrict__ row_start, const unsigned* __restrict__ deg,
                            const int* __restrict__ ssrc, const float* __restrict__ sea,
                            const float* __restrict__ We1, const float* __restrict__ att1,
                            const float* __restrict__ b1,
                            const float* __restrict__ xl, const float* __restrict__ xr,
                            const float* __restrict__ Wl2, const float* __restrict__ bl2,
                            const float* __restrict__ Wr2, const float* __restrict__ br2,
                            float* __restrict__ xl2, float* __restrict__ xr2) {
    int node = blockIdx.x * (blockDim.x >> 6) + (threadIdx.x >> 6);
    int lane = threadIdx.x & 63;
    if (node >= N_NODES) return;
    int g  = lane >> 4;          // edge sub-stream 0..3
    int cl = lane & 15;          // channel-slot: channels 4cl..4cl+3
    unsigned start = row_start[node];
    unsigned cnt   = deg[node];

    float4 we[8];
#pragma unroll
    for (int k = 0; k < 8; k++) we[k] = *(const float4*)(We1 + k * HC + 4 * cl);
    float4 attv = *(const float4*)(att1 + 4 * cl);
    float4 xrv  = *(const float4*)(xr + (size_t)node * HC + 4 * cl);

    float mA = NEG_BIG, denA = 0.f, mB = NEG_BIG, denB = 0.f;
    float4 accA = make_float4(0.f,0.f,0.f,0.f), accB = make_float4(0.f,0.f,0.f,0.f);

    // prefetch (depth 1, two streams)
    bool vA_n, vB_n;
    float4 e0A_n, e1A_n, xA_n, e0B_n, e1B_n, xB_n;
    load_edge(ssrc, sea, xl, start, cnt, g,     cl, vA_n, e0A_n, e1A_n, xA_n);
    load_edge(ssrc, sea, xl, start, cnt, 4 + g, cl, vB_n, e0B_n, e1B_n, xB_n);

    for (unsigned j = 0; j < cnt; j += 8) {
        bool vA = vA_n, vB = vB_n;
        float4 e0A = e0A_n, e1A = e1A_n, xA = xA_n;
        float4 e0B = e0B_n, e1B = e1B_n, xB = xB_n;
        unsigned jn = j + 8;
        if (jn < cnt) {
            load_edge(ssrc, sea, xl, start, cnt, jn + g,     cl, vA_n, e0A_n, e1A_n, xA_n);
            load_edge(ssrc, sea, xl, start, cnt, jn + 4 + g, cl, vB_n, e0B_n, e1B_n, xB_n);
        }
        edge_update(we, attv, xrv, vA, e0A, e1A, xA, mA, denA, accA);
        edge_update(we, attv, xrv, vB, e0B, e1B, xB, mB, denB, accB);
    }
    // merge stream B into A (in-register)
    float m = fmaxf(mA, mB);
    float sA = __expf(mA - m), sB = __expf(mB - m);
    float den = denA * sA + denB * sB;
    float4 acc;
    acc.x = accA.x * sA + accB.x * sB;
    acc.y = accA.y * sA + accB.y * sB;
    acc.z = accA.z * sA + accB.z * sB;
    acc.w = accA.w * sA + accB.w * sB;

    // merge the 4 g-streams (lanes differing in bits 4,5)
    float M = m;
    M = fmaxf(M, __shfl_xor(M, 16));
    M = fmaxf(M, __shfl_xor(M, 32));
    float gs = __expf(m - M);
    den *= gs; acc.x *= gs; acc.y *= gs; acc.z *= gs; acc.w *= gs;
    den   += __shfl_xor(den, 16);   den   += __shfl_xor(den, 32);
    acc.x += __shfl_xor(acc.x, 16); acc.x += __shfl_xor(acc.x, 32);
    acc.y += __shfl_xor(acc.y, 16); acc.y += __shfl_xor(acc.y, 32);
    acc.z += __shfl_xor(acc.z, 16); acc.z += __shfl_xor(acc.z, 32);
    acc.w += __shfl_xor(acc.w, 16); acc.w += __shfl_xor(acc.w, 32);

    float4 b1v  = *(const float4*)(b1 + 4 * cl);
    float4 wl2v = *(const float4*)(Wl2 + 4 * cl);
    float4 wr2v = *(const float4*)(Wr2 + 4 * cl);
    float inv_den = 1.f / den;
    float4 o;
    o.x = acc.x * inv_den + b1v.x;
    o.y = acc.y * inv_den + b1v.y;
    o.z = acc.z * inv_den + b1v.z;
    o.w = acc.w * inv_den + b1v.w;
    o.x = o.x > 0.f ? o.x : expm1f(o.x);
    o.y = o.y > 0.f ? o.y : expm1f(o.y);
    o.z = o.z > 0.f ? o.z : expm1f(o.z);
    o.w = o.w > 0.f ? o.w : expm1f(o.w);
    float sl = o.x*wl2v.x + o.y*wl2v.y + o.z*wl2v.z + o.w*wl2v.w;
    float sr = o.x*wr2v.x + o.y*wr2v.y + o.z*wr2v.z + o.w*wr2v.w;
#pragma unroll
    for (int off = 1; off <= 8; off <<= 1) {
        sl += __shfl_xor(sl, off);
        sr += __shfl_xor(sr, off);
    }
    if (lane == 0) {
        xl2[node] = sl + bl2[0];
        xr2[node] = sr + br2[0];
    }
}

// fused layer-2: one wave per node, lanes parallel over in-edges.
// ee2 = ea@We2 precomputed in scatter (see2).
__global__ void gat2_kernel(const unsigned* __restrict__ row_start, const unsigned* __restrict__ deg,
                            const int* __restrict__ sorted_src, const float* __restrict__ see2,
                            const float* __restrict__ att2,
                            const float* __restrict__ xl2, const float* __restrict__ xr2,
                            const float* __restrict__ b2, float* __restrict__ out) {
    int node = blockIdx.x * (blockDim.x >> 6) + (threadIdx.x >> 6);
    int lane = threadIdx.x & 63;
    if (node >= N_NODES) return;
    unsigned start = row_start[node];
    unsigned cnt   = deg[node];
    float xrv = xr2[node];
    float a2  = att2[0];
    float m = -INFINITY, den = 0.f, num = 0.f;
    for (unsigned base = 0; base < cnt; base += 64) {
        unsigned idx = base + lane;
        float logit = -INFINITY, xv = 0.f;
        if (idx < cnt) {
            int s = sorted_src[start + idx];
            float ee = see2[start + idx];
            xv = xl2[s];
            float v = xv + xrv + ee;
            v = v > 0.f ? v : NEG * v;
            logit = a2 * v;
        }
        float mm = logit;
        for (int off = 1; off < 64; off <<= 1) mm = fmaxf(mm, __shfl_xor(mm, off));
        float mnew = fmaxf(m, mm);
        float p  = (idx < cnt) ? __expf(logit - mnew) : 0.f;
        float pn = p * xv;
        for (int off = 1; off < 64; off <<= 1) {
            p  += __shfl_xor(p, off);
            pn += __shfl_xor(pn, off);
        }
        float scale = __expf(m - mnew);
        den = den * scale + p;
        num = num * scale + pn;
        m = mnew;
    }
    if (lane == 0) out[node] = num / den + b2[0];
}

extern "C" void kernel_launch(void* const* d_in, const int* in_sizes, int n_in,
                              void* d_out, int out_size, void* d_ws, size_t ws_size,
                              hipStream_t stream) {
    const float* x    = (const float*)d_in[0];
    const int*   ei   = (const int*)d_in[1];
    const float* ea   = (const float*)d_in[2];
    const float* Wl1  = (const float*)d_in[3];
    const float* bl1  = (const float*)d_in[4];
    const float* Wr1  = (const float*)d_in[5];
    const float* br1  = (const float*)d_in[6];
    const float* We1  = (const float*)d_in[7];
    const float* att1 = (const float*)d_in[8];
    const float* b1   = (const float*)d_in[9];
    const float* Wl2  = (const float*)d_in[10];
    const float* bl2  = (const float*)d_in[11];
    const float* Wr2  = (const float*)d_in[12];
    const float* br2  = (const float*)d_in[13];
    const float* We2  = (const float*)d_in[14];
    const float* att2 = (const float*)d_in[15];
    const float* b2   = (const float*)d_in[16];

    const int* src = ei;              // edge_index row 0
    const int* dst = ei + N_EDGES;    // edge_index row 1

    float* W = (float*)d_ws;
    size_t o = 0;
    float*    sum8      = W + o;               o += 8;
    float*    partials  = W + o;               o += MS_BLOCKS * 8;
    unsigned* deg       = (unsigned*)(W + o);  o += N_NODES;
    unsigned* local_inc = (unsigned*)(W + o);  o += N_NODES;
    unsigned* bsum      = (unsigned*)(W + o);  o += 128;
    unsigned* row_start = (unsigned*)(W + o);  o += N_NODES;
    unsigned* next      = (unsigned*)(W + o);  o += N_NODES;
    int*      ssrc      = (int*)(W + o);       o += N_ITEMS;
    float*    see2      = W + o;               o += N_ITEMS;
    o = (o + 3) & ~(size_t)3;
    float*    sea       = W + o;               o += (size_t)N_ITEMS * 8;
    float*    xl1       = W + o;               o += (size_t)N_NODES * HC;
    float*    xr1       = W + o;               o += (size_t)N_NODES * HC;
    float*    xl2       = W + o;               o += N_NODES;
    float*    xr2       = W + o;               o += N_NODES;

    mean_sum_kernel<<<MS_BLOCKS, 256, 0, stream>>>(ea, partials, deg);
    reduce_sum8<<<1, 64, 0, stream>>>(partials, sum8);
    hist_kernel<<<(N_EDGES + 255) / 256, 256, 0, stream>>>(dst, deg);
    scan1<<<SCAN_NB, SCAN_BS, 0, stream>>>(deg, local_inc, bsum);
    scan2<<<1, 128, 0, stream>>>(bsum);
    scan3<<<(N_NODES + 255) / 256, 256, 0, stream>>>(local_inc, deg, bsum, row_start, next);
    scatter_kernel<<<(N_ITEMS + 255) / 256, 256, 0, stream>>>(
        src, dst, ea, sum8, We2, next, ssrc, sea, see2);
    gemm1_kernel<<<N_NODES / 32, 256, 0, stream>>>(x, Wl1, bl1, Wr1, br1, xl1, xr1);
    gat1_kernel<<<(N_NODES + 3) / 4, 256, 0, stream>>>(
        row_start, deg, ssrc, sea, We1, att1, b1, xl1, xr1,
        Wl2, bl2, Wr2, br2, xl2, xr2);
    gat2_kernel<<<(N_NODES + 3) / 4, 256, 0, stream>>>(
        row_start, deg, ssrc, see2, att2, xl2, xr2, b2, (float*)d_out);
}

// Round 6
// 435.213 us; speedup vs baseline: 3.9506x; 1.0002x over previous
//
#include <hip/hip_runtime.h>
#include <math.h>

#define N_NODES 100000
#define N_EDGES 1600000
#define N_ITEMS (N_EDGES + N_NODES)   // edges + self loops
#define F_IN 128
#define F_E 8
#define HC 64      // H*C (layer-1 output width)
#define NHEAD 4
#define NEG 0.2f
#define SCAN_BS 1024
#define SCAN_NB ((N_NODES + SCAN_BS - 1) / SCAN_BS)   // 98
#define MS_BLOCKS 1024
#define NEG_BIG (-3.0e38f)

// per-block partial sums of edge_attr columns (no atomics); also inits deg=1
__global__ void mean_sum_kernel(const float* __restrict__ ea, float* __restrict__ partials,
                                unsigned* __restrict__ deg) {
    __shared__ float sh[4][8];
    int stride = gridDim.x * blockDim.x;
    for (int i = blockIdx.x * blockDim.x + threadIdx.x; i < N_NODES; i += stride)
        deg[i] = 1u;   // self loop
    float acc[8] = {0.f,0.f,0.f,0.f,0.f,0.f,0.f,0.f};
    for (int r = blockIdx.x * blockDim.x + threadIdx.x; r < N_EDGES; r += stride) {
        const float4* p = (const float4*)(ea + (size_t)r * 8);
        float4 a = p[0], b = p[1];
        acc[0] += a.x; acc[1] += a.y; acc[2] += a.z; acc[3] += a.w;
        acc[4] += b.x; acc[5] += b.y; acc[6] += b.z; acc[7] += b.w;
    }
    int wid  = threadIdx.x >> 6;
    int lane = threadIdx.x & 63;
#pragma unroll
    for (int k = 0; k < 8; k++) {
        float v = acc[k];
        for (int off = 32; off; off >>= 1) v += __shfl_down(v, off);
        if (lane == 0) sh[wid][k] = v;
    }
    __syncthreads();
    if (threadIdx.x < 8) {
        float s = sh[0][threadIdx.x] + sh[1][threadIdx.x] + sh[2][threadIdx.x] + sh[3][threadIdx.x];
        partials[blockIdx.x * 8 + threadIdx.x] = s;
    }
}

// one wave: reduce MS_BLOCKS x 8 partials -> sum8
__global__ void reduce_sum8(const float* __restrict__ partials, float* __restrict__ sum8) {
    int lane = threadIdx.x;       // 64 threads
    int c = lane & 7, g = lane >> 3;
    float s = 0.f;
    for (int b = g; b < MS_BLOCKS; b += 8) s += partials[b * 8 + c];
    s += __shfl_xor(s, 8);
    s += __shfl_xor(s, 16);
    s += __shfl_xor(s, 32);
    if (lane < 8) sum8[lane] = s;
}

__global__ void hist_kernel(const int* __restrict__ dst, unsigned* __restrict__ deg) {
    int e = blockIdx.x * blockDim.x + threadIdx.x;
    if (e < N_EDGES) atomicAdd(&deg[dst[e]], 1u);
}

// inclusive block scan of deg -> local_inc; per-block totals -> bsum
__global__ void scan1(const unsigned* __restrict__ deg, unsigned* __restrict__ local_inc,
                      unsigned* __restrict__ bsum) {
    __shared__ unsigned tmp[SCAN_BS];
    int i = blockIdx.x * SCAN_BS + threadIdx.x;
    unsigned v = (i < N_NODES) ? deg[i] : 0u;
    tmp[threadIdx.x] = v;
    __syncthreads();
    for (int off = 1; off < SCAN_BS; off <<= 1) {
        unsigned add = (threadIdx.x >= (unsigned)off) ? tmp[threadIdx.x - off] : 0u;
        __syncthreads();
        tmp[threadIdx.x] += add;
        __syncthreads();
    }
    if (i < N_NODES) local_inc[i] = tmp[threadIdx.x];
    if (threadIdx.x == SCAN_BS - 1) bsum[blockIdx.x] = tmp[threadIdx.x];
}

// exclusive scan of the 98 block sums (single block of 128)
__global__ void scan2(unsigned* __restrict__ bsum) {
    __shared__ unsigned tmp[128];
    int t = threadIdx.x;
    unsigned v = (t < SCAN_NB) ? bsum[t] : 0u;
    tmp[t] = v;
    __syncthreads();
    for (int off = 1; off < 128; off <<= 1) {
        unsigned add = (t >= off) ? tmp[t - off] : 0u;
        __syncthreads();
        tmp[t] += add;
        __syncthreads();
    }
    if (t < SCAN_NB) bsum[t] = tmp[t] - v;   // exclusive
}

__global__ void scan3(const unsigned* __restrict__ local_inc, const unsigned* __restrict__ deg,
                      const unsigned* __restrict__ bsum,
                      unsigned* __restrict__ row_start, unsigned* __restrict__ next) {
    int i = blockIdx.x * blockDim.x + threadIdx.x;
    if (i >= N_NODES) return;
    unsigned v = local_inc[i] - deg[i] + bsum[i / SCAN_BS];
    row_start[i] = v;
    next[i] = v;
}

// scatter edges (+ self loops) into destination-sorted order; also precompute
// see2 = ea @ We2 (scalar per item) for layer 2.
__global__ void scatter_kernel(const int* __restrict__ src, const int* __restrict__ dst,
                               const float* __restrict__ ea, const float* __restrict__ sum8,
                               const float* __restrict__ We2,
                               unsigned* __restrict__ next,
                               int* __restrict__ sorted_src, float* __restrict__ sorted_ea,
                               float* __restrict__ see2) {
    int item = blockIdx.x * blockDim.x + threadIdx.x;
    if (item >= N_ITEMS) return;
    int s, d;
    float4 a, b;
    if (item < N_EDGES) {
        s = src[item]; d = dst[item];
        const float4* p = (const float4*)(ea + (size_t)item * 8);
        a = p[0]; b = p[1];
    } else {
        s = d = item - N_EDGES;
        const float inv = 1.0f / N_EDGES;
        a = make_float4(sum8[0]*inv, sum8[1]*inv, sum8[2]*inv, sum8[3]*inv);
        b = make_float4(sum8[4]*inv, sum8[5]*inv, sum8[6]*inv, sum8[7]*inv);
    }
    float ee2 = a.x*We2[0] + a.y*We2[1] + a.z*We2[2] + a.w*We2[3]
              + b.x*We2[4] + b.y*We2[5] + b.z*We2[6] + b.w*We2[7];
    unsigned pos = atomicAdd(&next[d], 1u);
    sorted_src[pos] = s;
    see2[pos] = ee2;
    float4* q = (float4*)(sorted_ea + (size_t)pos * 8);
    q[0] = a; q[1] = b;
}

// xl = x@Wl + bl ; xr = x@Wr + br    (N x 128) @ (128 x 64)
__global__ __launch_bounds__(256) void gemm1_kernel(
        const float* __restrict__ x,
        const float* __restrict__ Wl, const float* __restrict__ bl,
        const float* __restrict__ Wr, const float* __restrict__ br,
        float* __restrict__ xl, float* __restrict__ xr) {
    __shared__ float xs_t[F_IN][36];      // [k][node], padded -> 18 KiB
    int t = threadIdx.x & 31;             // col-quad: combined cols 4t..4t+3
    int g = threadIdx.x >> 5;             // node-quad: nodes 4g..4g+3 of the tile
    const float* Wsel = (t < 16) ? Wl : Wr;
    const float* bsel = (t < 16) ? bl : br;
    int jc = (t < 16) ? 4 * t : 4 * t - HC;
    float4 bias = *(const float4*)(bsel + jc);
    float* dstp = (t < 16) ? xl : xr;

    int n0 = blockIdx.x * 32;             // N_NODES = 32*3125 exactly
    int row = threadIdx.x >> 3;           // 0..31
    int cq  = threadIdx.x & 7;            // col chunk
#pragma unroll
    for (int r = 0; r < 4; r++) {
        int c = cq * 4 + r * 32;
        float4 v = *(const float4*)(x + (size_t)(n0 + row) * F_IN + c);
        xs_t[c + 0][row] = v.x;
        xs_t[c + 1][row] = v.y;
        xs_t[c + 2][row] = v.z;
        xs_t[c + 3][row] = v.w;
    }
    __syncthreads();
    int nb = g * 4;
    float4 a0 = bias, a1 = bias, a2 = bias, a3 = bias;
#pragma unroll 4
    for (int k = 0; k < F_IN; k++) {
        float4 w  = *(const float4*)(Wsel + k * HC + jc);
        float4 xv = *(const float4*)&xs_t[k][nb];
        a0.x += w.x * xv.x; a0.y += w.y * xv.x; a0.z += w.z * xv.x; a0.w += w.w * xv.x;
        a1.x += w.x * xv.y; a1.y += w.y * xv.y; a1.z += w.z * xv.y; a1.w += w.w * xv.y;
        a2.x += w.x * xv.z; a2.y += w.y * xv.z; a2.z += w.z * xv.z; a2.w += w.w * xv.z;
        a3.x += w.x * xv.w; a3.y += w.y * xv.w; a3.z += w.z * xv.w; a3.w += w.w * xv.w;
    }
    *(float4*)(dstp + (size_t)(n0 + nb + 0) * HC + jc) = a0;
    *(float4*)(dstp + (size_t)(n0 + nb + 1) * HC + jc) = a1;
    *(float4*)(dstp + (size_t)(n0 + nb + 2) * HC + jc) = a2;
    *(float4*)(dstp + (size_t)(n0 + nb + 3) * HC + jc) = a3;
}

__device__ __forceinline__ void load_edge(const int* __restrict__ ssrc,
                                          const float* __restrict__ sea,
                                          const float* __restrict__ xl,
                                          unsigned start, unsigned cnt, unsigned idx, int cl,
                                          bool& valid, float4& e0, float4& e1, float4& xv) {
    valid = (idx < cnt);
    unsigned sf = valid ? start + idx : start;
    int s = ssrc[sf];
    e0 = *(const float4*)(sea + (size_t)sf * 8);
    e1 = *(const float4*)(sea + (size_t)sf * 8 + 4);
    xv = *(const float4*)(xl + (size_t)s * HC + 4 * cl);
}

__device__ __forceinline__ void edge_update(const float4* __restrict__ we,
                                            const float4& attv, const float4& xrv,
                                            bool valid, const float4& ea0, const float4& ea1,
                                            const float4& xlv,
                                            float& m, float& den, float4& acc) {
    float4 v;
    v.x = xlv.x + xrv.x + ea0.x*we[0].x + ea0.y*we[1].x + ea0.z*we[2].x + ea0.w*we[3].x
                        + ea1.x*we[4].x + ea1.y*we[5].x + ea1.z*we[6].x + ea1.w*we[7].x;
    v.y = xlv.y + xrv.y + ea0.x*we[0].y + ea0.y*we[1].y + ea0.z*we[2].y + ea0.w*we[3].y
                        + ea1.x*we[4].y + ea1.y*we[5].y + ea1.z*we[6].y + ea1.w*we[7].y;
    v.z = xlv.z + xrv.z + ea0.x*we[0].z + ea0.y*we[1].z + ea0.z*we[2].z + ea0.w*we[3].z
                        + ea1.x*we[4].z + ea1.y*we[5].z + ea1.z*we[6].z + ea1.w*we[7].z;
    v.w = xlv.w + xrv.w + ea0.x*we[0].w + ea0.y*we[1].w + ea0.z*we[2].w + ea0.w*we[3].w
                        + ea1.x*we[4].w + ea1.y*we[5].w + ea1.z*we[6].w + ea1.w*we[7].w;
    v.x = v.x > 0.f ? v.x : NEG * v.x;
    v.y = v.y > 0.f ? v.y : NEG * v.y;
    v.z = v.z > 0.f ? v.z : NEG * v.z;
    v.w = v.w > 0.f ? v.w : NEG * v.w;
    float prod = v.x*attv.x + v.y*attv.y + v.z*attv.z + v.w*attv.w;
    prod += __shfl_xor(prod, 1);
    prod += __shfl_xor(prod, 2);      // per-head logit in each 4-lane cluster
    float logit = valid ? prod : NEG_BIG;
    float mnew  = fmaxf(m, logit);
    float scale = __expf(m - mnew);
    float p     = valid ? __expf(logit - mnew) : 0.f;
    den   = den   * scale + p;
    acc.x = acc.x * scale + p * xlv.x;
    acc.y = acc.y * scale + p * xlv.y;
    acc.z = acc.z * scale + p * xlv.z;
    acc.w = acc.w * scale + p * xlv.w;
    m = mnew;
}

// fused layer-1: one wave per node, 8 edges per iteration as TWO independent
// online-softmax streams (ILP to hide gather latency). 16 lanes/edge, 4 ch/lane.
__global__ void gat1_kernel(const unsigned* __restrict__ row_start, const unsigned* __restrict__ deg,
                            const int* __restrict__ ssrc, const float* __restrict__ sea,
                            const float* __restrict__ We1, const float* __restrict__ att1,
                            const float* __restrict__ b1,
                            const float* __restrict__ xl, const float* __restrict__ xr,
                            const float* __restrict__ Wl2, const float* __restrict__ bl2,
                            const float* __restrict__ Wr2, const float* __restrict__ br2,
                            float* __restrict__ xl2, float* __restrict__ xr2) {
    int node = blockIdx.x * (blockDim.x >> 6) + (threadIdx.x >> 6);
    int lane = threadIdx.x & 63;
    if (node >= N_NODES) return;
    int g  = lane >> 4;          // edge sub-stream 0..3
    int cl = lane & 15;          // channel-slot: channels 4cl..4cl+3
    unsigned start = row_start[node];
    unsigned cnt   = deg[node];

    float4 we[8];
#pragma unroll
    for (int k = 0; k < 8; k++) we[k] = *(const float4*)(We1 + k * HC + 4 * cl);
    float4 attv = *(const float4*)(att1 + 4 * cl);
    float4 xrv  = *(const float4*)(xr + (size_t)node * HC + 4 * cl);

    float mA = NEG_BIG, denA = 0.f, mB = NEG_BIG, denB = 0.f;
    float4 accA = make_float4(0.f,0.f,0.f,0.f), accB = make_float4(0.f,0.f,0.f,0.f);

    // prefetch (depth 1, two streams)
    bool vA_n, vB_n;
    float4 e0A_n, e1A_n, xA_n, e0B_n, e1B_n, xB_n;
    load_edge(ssrc, sea, xl, start, cnt, g,     cl, vA_n, e0A_n, e1A_n, xA_n);
    load_edge(ssrc, sea, xl, start, cnt, 4 + g, cl, vB_n, e0B_n, e1B_n, xB_n);

    for (unsigned j = 0; j < cnt; j += 8) {
        bool vA = vA_n, vB = vB_n;
        float4 e0A = e0A_n, e1A = e1A_n, xA = xA_n;
        float4 e0B = e0B_n, e1B = e1B_n, xB = xB_n;
        unsigned jn = j + 8;
        if (jn < cnt) {
            load_edge(ssrc, sea, xl, start, cnt, jn + g,     cl, vA_n, e0A_n, e1A_n, xA_n);
            load_edge(ssrc, sea, xl, start, cnt, jn + 4 + g, cl, vB_n, e0B_n, e1B_n, xB_n);
        }
        edge_update(we, attv, xrv, vA, e0A, e1A, xA, mA, denA, accA);
        edge_update(we, attv, xrv, vB, e0B, e1B, xB, mB, denB, accB);
    }
    // merge stream B into A (in-register)
    float m = fmaxf(mA, mB);
    float sA = __expf(mA - m), sB = __expf(mB - m);
    float den = denA * sA + denB * sB;
    float4 acc;
    acc.x = accA.x * sA + accB.x * sB;
    acc.y = accA.y * sA + accB.y * sB;
    acc.z = accA.z * sA + accB.z * sB;
    acc.w = accA.w * sA + accB.w * sB;

    // merge the 4 g-streams (lanes differing in bits 4,5)
    float M = m;
    M = fmaxf(M, __shfl_xor(M, 16));
    M = fmaxf(M, __shfl_xor(M, 32));
    float gs = __expf(m - M);
    den *= gs; acc.x *= gs; acc.y *= gs; acc.z *= gs; acc.w *= gs;
    den   += __shfl_xor(den, 16);   den   += __shfl_xor(den, 32);
    acc.x += __shfl_xor(acc.x, 16); acc.x += __shfl_xor(acc.x, 32);
    acc.y += __shfl_xor(acc.y, 16); acc.y += __shfl_xor(acc.y, 32);
    acc.z += __shfl_xor(acc.z, 16); acc.z += __shfl_xor(acc.z, 32);
    acc.w += __shfl_xor(acc.w, 16); acc.w += __shfl_xor(acc.w, 32);

    float4 b1v  = *(const float4*)(b1 + 4 * cl);
    float4 wl2v = *(const float4*)(Wl2 + 4 * cl);
    float4 wr2v = *(const float4*)(Wr2 + 4 * cl);
    float inv_den = 1.f / den;
    float4 o;
    o.x = acc.x * inv_den + b1v.x;
    o.y = acc.y * inv_den + b1v.y;
    o.z = acc.z * inv_den + b1v.z;
    o.w = acc.w * inv_den + b1v.w;
    o.x = o.x > 0.f ? o.x : expm1f(o.x);
    o.y = o.y > 0.f ? o.y : expm1f(o.y);
    o.z = o.z > 0.f ? o.z : expm1f(o.z);
    o.w = o.w > 0.f ? o.w : expm1f(o.w);
    float sl = o.x*wl2v.x + o.y*wl2v.y + o.z*wl2v.z + o.w*wl2v.w;
    float sr = o.x*wr2v.x + o.y*wr2v.y + o.z*wr2v.z + o.w*wr2v.w;
#pragma unroll
    for (int off = 1; off <= 8; off <<= 1) {
        sl += __shfl_xor(sl, off);
        sr += __shfl_xor(sr, off);
    }
    if (lane == 0) {
        xl2[node] = sl + bl2[0];
        xr2[node] = sr + br2[0];
    }
}

// fused layer-2: one wave per node, lanes parallel over in-edges.
// ee2 = ea@We2 precomputed in scatter (see2).
__global__ void gat2_kernel(const unsigned* __restrict__ row_start, const unsigned* __restrict__ deg,
                            const int* __restrict__ sorted_src, const float* __restrict__ see2,
                            const float* __restrict__ att2,
                            const float* __restrict__ xl2, const float* __restrict__ xr2,
                            const float* __restrict__ b2, float* __restrict__ out) {
    int node = blockIdx.x * (blockDim.x >> 6) + (threadIdx.x >> 6);
    int lane = threadIdx.x & 63;
    if (node >= N_NODES) return;
    unsigned start = row_start[node];
    unsigned cnt   = deg[node];
    float xrv = xr2[node];
    float a2  = att2[0];
    float m = -INFINITY, den = 0.f, num = 0.f;
    for (unsigned base = 0; base < cnt; base += 64) {
        unsigned idx = base + lane;
        float logit = -INFINITY, xv = 0.f;
        if (idx < cnt) {
            int s = sorted_src[start + idx];
            float ee = see2[start + idx];
            xv = xl2[s];
            float v = xv + xrv + ee;
            v = v > 0.f ? v : NEG * v;
            logit = a2 * v;
        }
        float mm = logit;
        for (int off = 1; off < 64; off <<= 1) mm = fmaxf(mm, __shfl_xor(mm, off));
        float mnew = fmaxf(m, mm);
        float p  = (idx < cnt) ? __expf(logit - mnew) : 0.f;
        float pn = p * xv;
        for (int off = 1; off < 64; off <<= 1) {
            p  += __shfl_xor(p, off);
            pn += __shfl_xor(pn, off);
        }
        float scale = __expf(m - mnew);
        den = den * scale + p;
        num = num * scale + pn;
        m = mnew;
    }
    if (lane == 0) out[node] = num / den + b2[0];
}

extern "C" void kernel_launch(void* const* d_in, const int* in_sizes, int n_in,
                              void* d_out, int out_size, void* d_ws, size_t ws_size,
                              hipStream_t stream) {
    const float* x    = (const float*)d_in[0];
    const int*   ei   = (const int*)d_in[1];
    const float* ea   = (const float*)d_in[2];
    const float* Wl1  = (const float*)d_in[3];
    const float* bl1  = (const float*)d_in[4];
    const float* Wr1  = (const float*)d_in[5];
    const float* br1  = (const float*)d_in[6];
    const float* We1  = (const float*)d_in[7];
    const float* att1 = (const float*)d_in[8];
    const float* b1   = (const float*)d_in[9];
    const float* Wl2  = (const float*)d_in[10];
    const float* bl2  = (const float*)d_in[11];
    const float* Wr2  = (const float*)d_in[12];
    const float* br2  = (const float*)d_in[13];
    const float* We2  = (const float*)d_in[14];
    const float* att2 = (const float*)d_in[15];
    const float* b2   = (const float*)d_in[16];

    const int* src = ei;              // edge_index row 0
    const int* dst = ei + N_EDGES;    // edge_index row 1

    float* W = (float*)d_ws;
    size_t o = 0;
    float*    sum8      = W + o;               o += 8;
    float*    partials  = W + o;               o += MS_BLOCKS * 8;
    unsigned* deg       = (unsigned*)(W + o);  o += N_NODES;
    unsigned* local_inc = (unsigned*)(W + o);  o += N_NODES;
    unsigned* bsum      = (unsigned*)(W + o);  o += 128;
    unsigned* row_start = (unsigned*)(W + o);  o += N_NODES;
    unsigned* next      = (unsigned*)(W + o);  o += N_NODES;
    int*      ssrc      = (int*)(W + o);       o += N_ITEMS;
    float*    see2      = W + o;               o += N_ITEMS;
    o = (o + 3) & ~(size_t)3;
    float*    sea       = W + o;               o += (size_t)N_ITEMS * 8;
    float*    xl1       = W + o;               o += (size_t)N_NODES * HC;
    float*    xr1       = W + o;               o += (size_t)N_NODES * HC;
    float*    xl2       = W + o;               o += N_NODES;
    float*    xr2       = W + o;               o += N_NODES;

    mean_sum_kernel<<<MS_BLOCKS, 256, 0, stream>>>(ea, partials, deg);
    reduce_sum8<<<1, 64, 0, stream>>>(partials, sum8);
    hist_kernel<<<(N_EDGES + 255) / 256, 256, 0, stream>>>(dst, deg);
    scan1<<<SCAN_NB, SCAN_BS, 0, stream>>>(deg, local_inc, bsum);
    scan2<<<1, 128, 0, stream>>>(bsum);
    scan3<<<(N_NODES + 255) / 256, 256, 0, stream>>>(local_inc, deg, bsum, row_start, next);
    scatter_kernel<<<(N_ITEMS + 255) / 256, 256, 0, stream>>>(
        src, dst, ea, sum8, We2, next, ssrc, sea, see2);
    gemm1_kernel<<<N_NODES / 32, 256, 0, stream>>>(x, Wl1, bl1, Wr1, br1, xl1, xr1);
    gat1_kernel<<<(N_NODES + 3) / 4, 256, 0, stream>>>(
        row_start, deg, ssrc, sea, We1, att1, b1, xl1, xr1,
        Wl2, bl2, Wr2, br2, xl2, xr2);
    gat2_kernel<<<(N_NODES + 3) / 4, 256, 0, stream>>>(
        row_start, deg, ssrc, see2, att2, xl2, xr2, b2, (float*)d_out);
}